// Round 1
// baseline (5450.335 us; speedup 1.0000x reference)
//
#include <hip/hip_runtime.h>
#include <math.h>

// Problem constants
// B=2 T=2048 D=1024 H=16 DH=64 E=16 K=2 F=2048 CAP=640 DP=256 NPRIM=512
#define NTOK 4096

// ---------------- RMSNorm: one block per token ----------------
__global__ __launch_bounds__(256) void rmsnorm_k(const float* __restrict__ x,
                                                 const float* __restrict__ w,
                                                 float* __restrict__ y) {
  const long n = blockIdx.x;
  const int t = threadIdx.x;
  const float4 v = ((const float4*)(x + n * 1024))[t];
  float ss = v.x * v.x + v.y * v.y + v.z * v.z + v.w * v.w;
#pragma unroll
  for (int o = 32; o > 0; o >>= 1) ss += __shfl_down(ss, o);
  __shared__ float red[4];
  __shared__ float sc;
  if ((t & 63) == 0) red[t >> 6] = ss;
  __syncthreads();
  if (t == 0) sc = rsqrtf((red[0] + red[1] + red[2] + red[3]) * (1.0f / 1024.0f) + 1e-6f);
  __syncthreads();
  const float s = sc;
  const float4 wv = ((const float4*)w)[t];
  float4 o;
  o.x = v.x * s * wv.x; o.y = v.y * s * wv.y; o.z = v.z * s * wv.z; o.w = v.w * s * wv.w;
  ((float4*)(y + n * 1024))[t] = o;
}

// ---------------- Generic 64x64-tile fp32 GEMM ----------------
// MODE: 0=store alpha*acc, 1=C+=alpha*acc, 2=C=silu(alpha*acc), 3=C+=rowscale[row]*alpha*acc
// BT: 1 -> B is (N,K) row-major (C=A*B^T); 0 -> B is (K,N) row-major (C=A*B)
template <int MODE, int BT>
__global__ __launch_bounds__(256) void gemm_tile(const float* __restrict__ A,
                                                 const float* __restrict__ B,
                                                 float* __restrict__ C,
                                                 int M, int N, int K,
                                                 long sA, long sB, long sC,
                                                 float alpha,
                                                 const float* __restrict__ rowscale) {
  A += (long)blockIdx.z * sA;
  B += (long)blockIdx.z * sB;
  C += (long)blockIdx.z * sC;
  __shared__ float As[16][68];
  __shared__ float Bs[16][68];
  const int tid = threadIdx.x;
  const int m0 = blockIdx.y << 6;
  const int n0 = blockIdx.x << 6;
  const int r0 = (tid >> 4) << 2;
  const int c0 = (tid & 15) << 2;
  const int lm = tid >> 2;        // 0..63 (row for A / B^T loads)
  const int lk = (tid & 3) << 2;  // 0,4,8,12
  const int bk = tid >> 4;        // 0..15 (k for B-normal loads)
  const int bn = (tid & 15) << 2; // 0..60
  float acc[4][4] = {};
  for (int k0 = 0; k0 < K; k0 += 16) {
    __syncthreads();
    {
      const float4 av = *(const float4*)(A + (long)(m0 + lm) * K + k0 + lk);
      As[lk + 0][lm] = av.x; As[lk + 1][lm] = av.y;
      As[lk + 2][lm] = av.z; As[lk + 3][lm] = av.w;
    }
    if (BT) {
      const float4 bv = *(const float4*)(B + (long)(n0 + lm) * K + k0 + lk);
      Bs[lk + 0][lm] = bv.x; Bs[lk + 1][lm] = bv.y;
      Bs[lk + 2][lm] = bv.z; Bs[lk + 3][lm] = bv.w;
    } else {
      *(float4*)&Bs[bk][bn] = *(const float4*)(B + (long)(k0 + bk) * N + n0 + bn);
    }
    __syncthreads();
#pragma unroll
    for (int kk = 0; kk < 16; ++kk) {
      const float4 a = *(const float4*)&As[kk][r0];
      const float4 b = *(const float4*)&Bs[kk][c0];
      const float ar[4] = {a.x, a.y, a.z, a.w};
      const float br[4] = {b.x, b.y, b.z, b.w};
#pragma unroll
      for (int i = 0; i < 4; ++i)
#pragma unroll
        for (int j = 0; j < 4; ++j) acc[i][j] = fmaf(ar[i], br[j], acc[i][j]);
    }
  }
#pragma unroll
  for (int i = 0; i < 4; ++i) {
    const int row = m0 + r0 + i;
    float* cp = C + (long)row * N + n0 + c0;
    float rs = 0.f;
    if (MODE == 3) rs = rowscale[row];
#pragma unroll
    for (int j = 0; j < 4; ++j) {
      const float v = alpha * acc[i][j];
      if (MODE == 0) cp[j] = v;
      else if (MODE == 1) cp[j] += v;
      else if (MODE == 2) cp[j] = v / (1.f + expf(-v));
      else cp[j] += rs * v;
    }
  }
}

// ---------------- RoPE + split/transpose to [bh][t][dh] ----------------
__global__ __launch_bounds__(256) void rope_split_k(const float* __restrict__ qkv,
                                                    float* __restrict__ Q,
                                                    float* __restrict__ Kd,
                                                    float* __restrict__ V) {
  const int n = blockIdx.x;
  const int b = n >> 11;
  const int t = n & 2047;
  const float l2t = 13.287712379549449f; // log2(10000)
  const float* row = qkv + (long)n * 3072;
  for (int idx = threadIdx.x; idx < 3072; idx += 256) {
    const int which = idx >> 10;
    const int rem = idx & 1023;
    const int h = rem >> 6;
    const int d = rem & 63;
    const float val = row[idx];
    float out;
    if (which == 2) {
      out = val;
    } else {
      const float inv = exp2f(-l2t * (float)(d & 31) * (1.0f / 32.0f));
      const float ang = (float)t * inv;
      const float c = cosf(ang), s = sinf(ang);
      const float other = (d < 32) ? -row[which * 1024 + h * 64 + d + 32]
                                   : row[which * 1024 + h * 64 + d - 32];
      out = val * c + other * s;
    }
    const long o = ((long)(b * 16 + h) * 2048 + t) * 64 + d;
    if (which == 0) Q[o] = out;
    else if (which == 1) Kd[o] = out;
    else V[o] = out;
  }
}

// ---------------- Flash-style causal attention ----------------
// grid: (32 q-tiles, 32 bh). Writes O in [b][t][h*64+dh] = [n][D] layout.
__global__ __launch_bounds__(256) void flash_k(const float* __restrict__ Q,
                                               const float* __restrict__ Kg,
                                               const float* __restrict__ V,
                                               float* __restrict__ O) {
  const int qb = blockIdx.x;
  const int bh = blockIdx.y;
  const int b = bh >> 4, h = bh & 15;
  const int q0 = qb << 6;
  __shared__ float Qs[64][64];
  __shared__ float Ks[64][64];
  __shared__ float Vs[64][64];
  __shared__ float Ss[64][65];
  __shared__ float mrow[64], lrow[64], arow[64];
  __shared__ float red[64][4];
  const int tid = threadIdx.x;
  const int r0 = (tid >> 4) << 2;
  const int c0 = (tid & 15) << 2;
  const int rr = tid >> 2;
  const int seg = tid & 3;
  const long base_q = ((long)bh * 2048 + q0) * 64;
#pragma unroll
  for (int rep = 0; rep < 4; ++rep) {
    const int f = tid + rep * 256;
    const int r = f >> 4;
    const int c4 = (f & 15) << 2;
    *(float4*)&Qs[r][c4] = *(const float4*)(Q + base_q + r * 64 + c4);
  }
  if (tid < 64) { mrow[tid] = -3.0e38f; lrow[tid] = 0.f; }
  float o_acc[4][4] = {};
  for (int kb = 0; kb <= qb; ++kb) {
    const int k0 = kb << 6;
    const long base_k = ((long)bh * 2048 + k0) * 64;
    __syncthreads();
#pragma unroll
    for (int rep = 0; rep < 4; ++rep) {
      const int f = tid + rep * 256;
      const int r = f >> 4;
      const int c4 = (f & 15) << 2;
      *(float4*)&Ks[r][c4] = *(const float4*)(Kg + base_k + r * 64 + c4);
      *(float4*)&Vs[r][c4] = *(const float4*)(V + base_k + r * 64 + c4);
    }
    __syncthreads();
    float s[4][4] = {};
#pragma unroll
    for (int dq = 0; dq < 16; ++dq) {
      float4 qv[4], kv[4];
#pragma unroll
      for (int i = 0; i < 4; ++i) qv[i] = *(const float4*)&Qs[r0 + i][dq << 2];
#pragma unroll
      for (int j = 0; j < 4; ++j) kv[j] = *(const float4*)&Ks[c0 + j][dq << 2];
#pragma unroll
      for (int i = 0; i < 4; ++i)
#pragma unroll
        for (int j = 0; j < 4; ++j)
          s[i][j] += qv[i].x * kv[j].x + qv[i].y * kv[j].y +
                     qv[i].z * kv[j].z + qv[i].w * kv[j].w;
    }
    const bool diag = (kb == qb);
#pragma unroll
    for (int i = 0; i < 4; ++i)
#pragma unroll
      for (int j = 0; j < 4; ++j) {
        float v = s[i][j] * 0.125f;
        if (diag && (c0 + j) > (r0 + i)) v = -1.0e30f;
        Ss[r0 + i][c0 + j] = v;
      }
    __syncthreads();
    float mx = -3.0e38f;
#pragma unroll
    for (int c = 0; c < 16; ++c) mx = fmaxf(mx, Ss[rr][seg * 16 + c]);
    red[rr][seg] = mx;
    __syncthreads();
    if (tid < 64) {
      const float mo = mrow[tid];
      float mn = fmaxf(fmaxf(red[tid][0], red[tid][1]), fmaxf(red[tid][2], red[tid][3]));
      mn = fmaxf(mn, mo);
      mrow[tid] = mn;
      arow[tid] = expf(mo - mn);
    }
    __syncthreads();
    const float mn = mrow[rr];
    float ps = 0.f;
#pragma unroll
    for (int c = 0; c < 16; ++c) {
      const float p = expf(Ss[rr][seg * 16 + c] - mn);
      Ss[rr][seg * 16 + c] = p;
      ps += p;
    }
    red[rr][seg] = ps;
    __syncthreads();
    if (tid < 64)
      lrow[tid] = lrow[tid] * arow[tid] + red[tid][0] + red[tid][1] + red[tid][2] + red[tid][3];
#pragma unroll
    for (int i = 0; i < 4; ++i) {
      const float al = arow[r0 + i];
#pragma unroll
      for (int j = 0; j < 4; ++j) o_acc[i][j] *= al;
    }
    for (int kk = 0; kk < 64; ++kk) {
      const float4 vv = *(const float4*)&Vs[kk][c0];
#pragma unroll
      for (int i = 0; i < 4; ++i) {
        const float p = Ss[r0 + i][kk];
        o_acc[i][0] += p * vv.x; o_acc[i][1] += p * vv.y;
        o_acc[i][2] += p * vv.z; o_acc[i][3] += p * vv.w;
      }
    }
  }
  __syncthreads();
#pragma unroll
  for (int i = 0; i < 4; ++i) {
    const float il = 1.f / lrow[r0 + i];
    float4 ov;
    ov.x = o_acc[i][0] * il; ov.y = o_acc[i][1] * il;
    ov.z = o_acc[i][2] * il; ov.w = o_acc[i][3] * il;
    *(float4*)(O + ((long)(b * 2048 + q0 + r0 + i)) * 1024 + h * 64 + c0) = ov;
  }
}

// ---------------- Router: logits, softmax, top-2, aux partials ----------------
__global__ __launch_bounds__(256) void router_k(const float* __restrict__ xn,
                                                const float* __restrict__ rw,
                                                int* __restrict__ topi,
                                                float* __restrict__ topw,
                                                float* __restrict__ cnt,
                                                float* __restrict__ psum) {
  const int n = blockIdx.x;
  const int e = threadIdx.x >> 4;
  const int t = threadIdx.x & 15;
  float s = 0.f;
  const float* xr = xn + (long)n * 1024;
  const float* wr = rw + (long)e * 1024;
  for (int j = 0; j < 64; ++j) {
    const int d = t + (j << 4);
    s += xr[d] * wr[d];
  }
  __shared__ float part[16][17];
  part[e][t] = s;
  __syncthreads();
  if (threadIdx.x == 0) {
    float logits[16];
    for (int ee = 0; ee < 16; ++ee) {
      float acc = 0.f;
      for (int j = 0; j < 16; ++j) acc += part[ee][j];
      logits[ee] = acc;
    }
    float mx = logits[0];
    for (int ee = 1; ee < 16; ++ee) mx = fmaxf(mx, logits[ee]);
    float p[16];
    float Z = 0.f;
    for (int ee = 0; ee < 16; ++ee) { p[ee] = expf(logits[ee] - mx); Z += p[ee]; }
    const float iz = 1.f / Z;
    for (int ee = 0; ee < 16; ++ee) p[ee] *= iz;
    int i1 = 0;
    for (int ee = 1; ee < 16; ++ee) if (p[ee] > p[i1]) i1 = ee;  // strict > : lowest index wins ties (jax)
    int i2 = (i1 == 0) ? 1 : 0;
    for (int ee = 0; ee < 16; ++ee) if (ee != i1 && p[ee] > p[i2]) i2 = ee;
    const float sw = p[i1] + p[i2];
    topi[2 * n] = i1; topi[2 * n + 1] = i2;
    topw[2 * n] = p[i1] / sw; topw[2 * n + 1] = p[i2] / sw;
    atomicAdd(&cnt[i1], 1.f);
    atomicAdd(&cnt[i2], 1.f);
    for (int ee = 0; ee < 16; ++ee) atomicAdd(&psum[ee], p[ee]);
  }
}

// ---------------- Capacity positions (order-sensitive serial scan) ----------------
__global__ __launch_bounds__(256) void pos_k(const int* __restrict__ topi,
                                             int* __restrict__ slot,
                                             int* __restrict__ keep) {
  __shared__ int fi[8192];
  for (int i = threadIdx.x; i < 8192; i += 256) fi[i] = topi[i];
  __syncthreads();
  const int e = threadIdx.x;
  if (e < 16) {
    int count = 0;
    for (int i = 0; i < 8192; ++i) {
      if (fi[i] == e) {
        slot[i] = (count < 640) ? count : 639;
        keep[i] = (count < 640) ? 1 : 0;
        ++count;
      }
    }
  }
}

__global__ __launch_bounds__(256) void scatter_k(const float* __restrict__ xn,
                                                 const int* __restrict__ topi,
                                                 const int* __restrict__ slot,
                                                 const int* __restrict__ keep,
                                                 float* __restrict__ buf) {
  const int i = blockIdx.x;
  if (!keep[i]) return;
  const int n = i >> 1;
  const long dst = ((long)topi[i] * 640 + slot[i]) * 1024;
  ((float4*)(buf + dst))[threadIdx.x] = ((const float4*)(xn + (long)n * 1024))[threadIdx.x];
}

__global__ __launch_bounds__(256) void gather_k(const float* __restrict__ yb,
                                                const int* __restrict__ topi,
                                                const int* __restrict__ slot,
                                                const int* __restrict__ keep,
                                                const float* __restrict__ topw,
                                                float* __restrict__ xb) {
  const int n = blockIdx.x;
  const int t = threadIdx.x;
  float4 acc = make_float4(0.f, 0.f, 0.f, 0.f);
#pragma unroll
  for (int k = 0; k < 2; ++k) {
    const int i = 2 * n + k;
    if (keep[i]) {
      const float wgt = topw[i];
      const float4 v = ((const float4*)(yb + ((long)topi[i] * 640 + slot[i]) * 1024))[t];
      acc.x += wgt * v.x; acc.y += wgt * v.y; acc.z += wgt * v.z; acc.w += wgt * v.w;
    }
  }
  float4* dp = (float4*)(xb + (long)n * 1024) + t;
  float4 cur = *dp;
  cur.x += acc.x; cur.y += acc.y; cur.z += acc.z; cur.w += acc.w;
  *dp = cur;
}

__global__ void aux_k(const float* __restrict__ cnt, const float* __restrict__ psum,
                      float* __restrict__ out) {
  if (threadIdx.x == 0) {
    float s = 0.f;
    for (int e = 0; e < 16; ++e)
      s += (cnt[e] * (1.f / 4096.f)) * (psum[e] * (1.f / 4096.f));
    out[0] = 16.f * s;
  }
}

// ---------------- tou: softmax over 512, sigmoid gate ----------------
__global__ __launch_bounds__(256) void softmax512_k(float* __restrict__ sc) {
  const long n = blockIdx.x;
  float2* row = (float2*)(sc + n * 512);
  const int t = threadIdx.x;
  float2 v = row[t];
  float mx = fmaxf(v.x, v.y);
#pragma unroll
  for (int o = 32; o > 0; o >>= 1) mx = fmaxf(mx, __shfl_down(mx, o));
  __shared__ float red[4];
  __shared__ float bm, bz;
  if ((t & 63) == 0) red[t >> 6] = mx;
  __syncthreads();
  if (t == 0) bm = fmaxf(fmaxf(red[0], red[1]), fmaxf(red[2], red[3]));
  __syncthreads();
  const float M = bm;
  const float e0 = expf(v.x - M), e1 = expf(v.y - M);
  float s = e0 + e1;
#pragma unroll
  for (int o = 32; o > 0; o >>= 1) s += __shfl_down(s, o);
  if ((t & 63) == 0) red[t >> 6] = s;
  __syncthreads();
  if (t == 0) bz = 1.f / (red[0] + red[1] + red[2] + red[3]);
  __syncthreads();
  row[t] = make_float2(e0 * bz, e1 * bz);
}

__global__ __launch_bounds__(256) void gate_k(const float* __restrict__ xn,
                                              const float* __restrict__ gw,
                                              const float* __restrict__ gb,
                                              float* __restrict__ gate) {
  const long n = blockIdx.x;
  const int t = threadIdx.x;
  const float4 v = ((const float4*)(xn + n * 1024))[t];
  const float4 g = ((const float4*)gw)[t];
  float s = v.x * g.x + v.y * g.y + v.z * g.z + v.w * g.w;
#pragma unroll
  for (int o = 32; o > 0; o >>= 1) s += __shfl_down(s, o);
  __shared__ float red[4];
  if ((t & 63) == 0) red[t >> 6] = s;
  __syncthreads();
  if (t == 0) {
    const float tot = red[0] + red[1] + red[2] + red[3] + gb[0];
    gate[n] = 1.f / (1.f + expf(-tot));
  }
}

extern "C" void kernel_launch(void* const* d_in, const int* in_sizes, int n_in,
                              void* d_out, int out_size, void* d_ws, size_t ws_size,
                              hipStream_t stream) {
  (void)in_sizes; (void)n_in; (void)out_size; (void)ws_size;
  const float* x    = (const float*)d_in[0];
  const float* prim = (const float*)d_in[1];
  const float* n1w  = (const float*)d_in[2];
  const float* qkvw = (const float*)d_in[3];
  const float* aow  = (const float*)d_in[4];
  const float* n2w  = (const float*)d_in[5];
  const float* rw   = (const float*)d_in[6];
  const float* w1   = (const float*)d_in[7];
  const float* w2   = (const float*)d_in[8];
  const float* n3w  = (const float*)d_in[9];
  const float* tqw  = (const float*)d_in[10];
  const float* tkw  = (const float*)d_in[11];
  const float* tvw  = (const float*)d_in[12];
  const float* tow  = (const float*)d_in[13];
  const float* tgw  = (const float*)d_in[14];
  const float* tgb  = (const float*)d_in[15];

  float* xbuf = (float*)d_out;        // running residual lives in d_out
  float* aux  = xbuf + 4194304;

  float* ws = (float*)d_ws;
  float* xn = ws;                     // 4,194,304 floats (persist per phase)
  float* ph = ws + 4194304;           // phase-shared region
  // phase A (attention)
  float* qkv   = ph;                  // 12,582,912
  float* qr    = ph + 12582912;       // 4,194,304
  float* kr    = qr + 4194304;
  float* vr    = kr + 4194304;
  float* attnx = vr + 4194304;
  // phase B (MoE) — aliases phase A
  int*   topi = (int*)ph;             // 8192
  float* topw = ph + 8192;            // 8192
  int*   slot = (int*)(ph + 16384);   // 8192
  int*   keep = (int*)(ph + 24576);   // 8192
  float* cnt  = ph + 32768;           // 16
  float* psum = ph + 32784;           // 16
  float* mbuf = ph + 65536;           // 10,485,760 (E*CAP*D)
  float* hbuf = mbuf + 10485760;      // 20,971,520 (E*CAP*F)
  float* ybuf = hbuf + 20971520;      // 10,485,760
  // phase C (tou) — aliases again
  float* tq   = ph;                   // 1,048,576
  float* tk   = tq + 1048576;         // 131,072
  float* tv   = tk + 131072;          // 131,072
  float* tsc  = tv + 131072;          // 2,097,152
  float* tav  = tsc + 2097152;        // 1,048,576
  float* gate = tav + 1048576;        // 4096

  // ---- phase A: x += rope_attention(rmsnorm(x)) ----
  hipMemcpyAsync(xbuf, x, (size_t)4194304 * 4, hipMemcpyDeviceToDevice, stream);
  rmsnorm_k<<<4096, 256, 0, stream>>>(xbuf, n1w, xn);
  gemm_tile<0, 1><<<dim3(3072 / 64, 4096 / 64, 1), 256, 0, stream>>>(
      xn, qkvw, qkv, 4096, 3072, 1024, 0, 0, 0, 1.f, nullptr);
  rope_split_k<<<4096, 256, 0, stream>>>(qkv, qr, kr, vr);
  flash_k<<<dim3(32, 32), 256, 0, stream>>>(qr, kr, vr, attnx);
  gemm_tile<1, 1><<<dim3(1024 / 64, 4096 / 64, 1), 256, 0, stream>>>(
      attnx, aow, xbuf, 4096, 1024, 1024, 0, 0, 0, 1.f, nullptr);

  // ---- phase B: MoE ----
  rmsnorm_k<<<4096, 256, 0, stream>>>(xbuf, n2w, xn);
  hipMemsetAsync(cnt, 0, 32 * 4, stream);
  router_k<<<4096, 256, 0, stream>>>(xn, rw, topi, topw, cnt, psum);
  pos_k<<<1, 256, 0, stream>>>(topi, slot, keep);
  hipMemsetAsync(mbuf, 0, (size_t)10485760 * 4, stream);
  scatter_k<<<8192, 256, 0, stream>>>(xn, topi, slot, keep, mbuf);
  gemm_tile<2, 0><<<dim3(2048 / 64, 640 / 64, 16), 256, 0, stream>>>(
      mbuf, w1, hbuf, 640, 2048, 1024,
      (long)640 * 1024, (long)1024 * 2048, (long)640 * 2048, 1.f, nullptr);
  gemm_tile<0, 0><<<dim3(1024 / 64, 640 / 64, 16), 256, 0, stream>>>(
      hbuf, w2, ybuf, 640, 1024, 2048,
      (long)640 * 2048, (long)2048 * 1024, (long)640 * 1024, 1.f, nullptr);
  gather_k<<<4096, 256, 0, stream>>>(ybuf, topi, slot, keep, topw, xbuf);
  aux_k<<<1, 64, 0, stream>>>(cnt, psum, aux);

  // ---- phase C: tou cross-attn ----
  rmsnorm_k<<<4096, 256, 0, stream>>>(xbuf, n3w, xn);
  gemm_tile<0, 1><<<dim3(256 / 64, 4096 / 64, 1), 256, 0, stream>>>(
      xn, tqw, tq, 4096, 256, 1024, 0, 0, 0, 1.f, nullptr);
  gemm_tile<0, 1><<<dim3(256 / 64, 512 / 64, 1), 256, 0, stream>>>(
      prim, tkw, tk, 512, 256, 256, 0, 0, 0, 1.f, nullptr);
  gemm_tile<0, 1><<<dim3(256 / 64, 512 / 64, 1), 256, 0, stream>>>(
      prim, tvw, tv, 512, 256, 256, 0, 0, 0, 1.f, nullptr);
  gemm_tile<0, 1><<<dim3(512 / 64, 4096 / 64, 1), 256, 0, stream>>>(
      tq, tk, tsc, 4096, 512, 256, 0, 0, 0, 0.0625f, nullptr);
  softmax512_k<<<4096, 256, 0, stream>>>(tsc);
  gemm_tile<0, 0><<<dim3(256 / 64, 4096 / 64, 1), 256, 0, stream>>>(
      tsc, tv, tav, 4096, 256, 512, 0, 0, 0, 1.f, nullptr);
  gate_k<<<4096, 256, 0, stream>>>(xn, tgw, tgb, gate);
  gemm_tile<3, 1><<<dim3(1024 / 64, 4096 / 64, 1), 256, 0, stream>>>(
      tav, tow, xbuf, 4096, 1024, 256, 0, 0, 0, 1.f, gate);
}

// Round 2
// 3418.211 us; speedup vs baseline: 1.5945x; 1.5945x over previous
//
#include <hip/hip_runtime.h>
#include <math.h>

// B=2 T=2048 D=1024 H=16 DH=64 E=16 K=2 F=2048 CAP=640 DP=256 NPRIM=512
typedef short bf16x8 __attribute__((ext_vector_type(8)));
typedef float f32x4 __attribute__((ext_vector_type(4)));

__device__ __forceinline__ unsigned short f2bf(float f) {
  union { float f; unsigned u; } v; v.f = f;
  return (unsigned short)((v.u + 0x7fff + ((v.u >> 16) & 1)) >> 16);
}
__device__ __forceinline__ float bf2f(unsigned short h) {
  union { unsigned u; float f; } v; v.u = ((unsigned)h) << 16;
  return v.f;
}

// ---------------- RMSNorm: fp32 out + bf16 out ----------------
__global__ __launch_bounds__(256) void rmsnorm_k(const float* __restrict__ x,
                                                 const float* __restrict__ w,
                                                 float* __restrict__ y,
                                                 unsigned short* __restrict__ yb) {
  const long n = blockIdx.x;
  const int t = threadIdx.x;
  const float4 v = ((const float4*)(x + n * 1024))[t];
  float ss = v.x * v.x + v.y * v.y + v.z * v.z + v.w * v.w;
#pragma unroll
  for (int o = 32; o > 0; o >>= 1) ss += __shfl_down(ss, o);
  __shared__ float red[4];
  __shared__ float sc;
  if ((t & 63) == 0) red[t >> 6] = ss;
  __syncthreads();
  if (t == 0) sc = rsqrtf((red[0] + red[1] + red[2] + red[3]) * (1.0f / 1024.0f) + 1e-6f);
  __syncthreads();
  const float s = sc;
  const float4 wv = ((const float4*)w)[t];
  float4 o;
  o.x = v.x * s * wv.x; o.y = v.y * s * wv.y; o.z = v.z * s * wv.z; o.w = v.w * s * wv.w;
  ((float4*)(y + n * 1024))[t] = o;
  ushort4 u = make_ushort4(f2bf(o.x), f2bf(o.y), f2bf(o.z), f2bf(o.w));
  *(ushort4*)(yb + n * 1024 + t * 4) = u;
}

// ---------------- fp32 -> bf16 flat ----------------
__global__ __launch_bounds__(256) void cvt_k(const float* __restrict__ in,
                                             unsigned short* __restrict__ out, int n4) {
  const int i = blockIdx.x * 256 + threadIdx.x;
  if (i >= n4) return;
  const float4 v = ((const float4*)in)[i];
  ((ushort4*)out)[i] = make_ushort4(f2bf(v.x), f2bf(v.y), f2bf(v.z), f2bf(v.w));
}

// ---------------- fp32 -> (hi, lo) bf16 split ----------------
__global__ __launch_bounds__(256) void split_k(const float* __restrict__ in,
                                               unsigned short* __restrict__ hi,
                                               unsigned short* __restrict__ lo, int n4) {
  const int i = blockIdx.x * 256 + threadIdx.x;
  if (i >= n4) return;
  const float4 v = ((const float4*)in)[i];
  ushort4 h = make_ushort4(f2bf(v.x), f2bf(v.y), f2bf(v.z), f2bf(v.w));
  ushort4 l = make_ushort4(f2bf(v.x - bf2f(h.x)), f2bf(v.y - bf2f(h.y)),
                           f2bf(v.z - bf2f(h.z)), f2bf(v.w - bf2f(h.w)));
  ((ushort4*)hi)[i] = h;
  ((ushort4*)lo)[i] = l;
}

// ---------------- transpose-convert: (R,C) fp32 -> (C,R) bf16, batched ----------------
__global__ __launch_bounds__(256) void cvt_t_k(const float* __restrict__ in,
                                               unsigned short* __restrict__ out,
                                               int R, int C) {
  in += (size_t)blockIdx.z * R * C;
  out += (size_t)blockIdx.z * R * C;
  const int r0 = blockIdx.y * 32, c0 = blockIdx.x * 32;
  __shared__ float T[32][33];
  const int tid = threadIdx.x;
  const int li = tid >> 3;
  const int lj = (tid & 7) << 2;
  const float4 v = *(const float4*)(in + (size_t)(r0 + li) * C + c0 + lj);
  T[li][lj + 0] = v.x; T[li][lj + 1] = v.y; T[li][lj + 2] = v.z; T[li][lj + 3] = v.w;
  __syncthreads();
  ushort4 u = make_ushort4(f2bf(T[lj + 0][li]), f2bf(T[lj + 1][li]),
                           f2bf(T[lj + 2][li]), f2bf(T[lj + 3][li]));
  *(ushort4*)(out + (size_t)(c0 + li) * R + r0 + lj) = u;
}

// ---------------- bf16 MFMA GEMM: C(M,N) = alpha * A(M,K) x B(N,K)^T ----------------
// MODE: 0=f32 store, 1=f32 +=, 2=bf16 store, 3=bf16 silu store,
//       4=f32 += rowscale[row]*v, 5=f32 atomicAdd to rowmap token (MoE un-scatter)
template <int MODE>
__global__ __launch_bounds__(256) void bgemm(const unsigned short* __restrict__ A,
                                             const unsigned short* __restrict__ B,
                                             void* __restrict__ Cv,
                                             int M, int N, int K,
                                             long sA, long sB, long sC, float alpha,
                                             const float* __restrict__ rowscale,
                                             const int* __restrict__ rowmap,
                                             const float* __restrict__ roww) {
  __shared__ __align__(16) unsigned short As[128][40];
  __shared__ __align__(16) unsigned short Bs[128][40];
  const int tid = threadIdx.x;
  const int z = blockIdx.z;
  const unsigned short* Ag = A + (size_t)z * sA;
  const unsigned short* Bg = B + (size_t)z * sB;
  const int m0 = blockIdx.y * 128, n0 = blockIdx.x * 128;
  const int lane = tid & 63;
  const int wid = tid >> 6;
  const int wm = (wid >> 1) * 64, wn = (wid & 1) * 64;
  const int fr = lane & 15, fq = lane >> 4;
  const int lr = tid >> 2, lk = (tid & 3) * 8;
  f32x4 acc[4][4] = {};
  const unsigned short* Ap0 = Ag + (size_t)(m0 + lr) * K + lk;
  const unsigned short* Ap1 = Ag + (size_t)(m0 + lr + 64) * K + lk;
  const unsigned short* Bp0 = Bg + (size_t)(n0 + lr) * K + lk;
  const unsigned short* Bp1 = Bg + (size_t)(n0 + lr + 64) * K + lk;
  uint4 a0 = *(const uint4*)Ap0, a1 = *(const uint4*)Ap1;
  uint4 b0 = *(const uint4*)Bp0, b1 = *(const uint4*)Bp1;
  for (int k0 = 0;;) {
    __syncthreads();
    *(uint4*)&As[lr][lk] = a0; *(uint4*)&As[lr + 64][lk] = a1;
    *(uint4*)&Bs[lr][lk] = b0; *(uint4*)&Bs[lr + 64][lk] = b1;
    __syncthreads();
    k0 += 32;
    if (k0 < K) {
      a0 = *(const uint4*)(Ap0 + k0); a1 = *(const uint4*)(Ap1 + k0);
      b0 = *(const uint4*)(Bp0 + k0); b1 = *(const uint4*)(Bp1 + k0);
    }
    bf16x8 af[4], bv[4];
#pragma unroll
    for (int i = 0; i < 4; ++i) af[i] = *(const bf16x8*)&As[wm + i * 16 + fr][fq * 8];
#pragma unroll
    for (int j = 0; j < 4; ++j) bv[j] = *(const bf16x8*)&Bs[wn + j * 16 + fr][fq * 8];
#pragma unroll
    for (int i = 0; i < 4; ++i)
#pragma unroll
      for (int j = 0; j < 4; ++j)
        acc[i][j] = __builtin_amdgcn_mfma_f32_16x16x32_bf16(af[i], bv[j], acc[i][j], 0, 0, 0);
    if (k0 >= K) break;
  }
#pragma unroll
  for (int i = 0; i < 4; ++i) {
#pragma unroll
    for (int reg = 0; reg < 4; ++reg) {
      const int row = m0 + wm + i * 16 + fq * 4 + reg;
      float rs = 0.f, wgt = 0.f;
      int tok = -1;
      if (MODE == 4) rs = rowscale[row];
      if (MODE == 5) {
        tok = rowmap[z * M + row];
        if (tok >= 0) wgt = roww[z * M + row];
      }
#pragma unroll
      for (int j = 0; j < 4; ++j) {
        const int col = n0 + wn + j * 16 + fr;
        const float v = alpha * acc[i][j][reg];
        if (MODE == 0) {
          ((float*)Cv + (size_t)z * sC)[(size_t)row * N + col] = v;
        } else if (MODE == 1) {
          float* p = (float*)Cv + (size_t)z * sC + (size_t)row * N + col;
          *p += v;
        } else if (MODE == 2) {
          ((unsigned short*)Cv + (size_t)z * sC)[(size_t)row * N + col] = f2bf(v);
        } else if (MODE == 3) {
          const float sv = v / (1.f + expf(-v));
          ((unsigned short*)Cv + (size_t)z * sC)[(size_t)row * N + col] = f2bf(sv);
        } else if (MODE == 4) {
          float* p = (float*)Cv + (size_t)row * N + col;
          *p += rs * v;
        } else if (MODE == 5) {
          if (tok >= 0) atomicAdd((float*)Cv + (size_t)tok * N + col, wgt * v);
        }
      }
    }
  }
}

// ---------------- RoPE + split/transpose to [bh][t][dh] ----------------
__global__ __launch_bounds__(256) void rope_split_k(const float* __restrict__ qkv,
                                                    float* __restrict__ Q,
                                                    float* __restrict__ Kd,
                                                    float* __restrict__ V) {
  const int n = blockIdx.x;
  const int b = n >> 11;
  const int t = n & 2047;
  const float l2t = 13.287712379549449f;
  const float* row = qkv + (long)n * 3072;
  for (int idx = threadIdx.x; idx < 3072; idx += 256) {
    const int which = idx >> 10;
    const int rem = idx & 1023;
    const int h = rem >> 6;
    const int d = rem & 63;
    const float val = row[idx];
    float out;
    if (which == 2) {
      out = val;
    } else {
      const float inv = exp2f(-l2t * (float)(d & 31) * (1.0f / 32.0f));
      const float ang = (float)t * inv;
      const float c = cosf(ang), s = sinf(ang);
      const float other = (d < 32) ? -row[which * 1024 + h * 64 + d + 32]
                                   : row[which * 1024 + h * 64 + d - 32];
      out = val * c + other * s;
    }
    const long o = ((long)(b * 16 + h) * 2048 + t) * 64 + d;
    if (which == 0) Q[o] = out;
    else if (which == 1) Kd[o] = out;
    else V[o] = out;
  }
}

// ---------------- Flash-style causal attention (fp32, swizzled LDS) ----------------
// slot of element (r,c): chunk ^= (r>>2)&7 to kill power-of-2 bank strides.
#define SWZ(r, c) (((r) << 6) + (((((c) >> 2) ^ (((r) >> 2) & 7)) & 15) << 2) + ((c) & 3))
__global__ __launch_bounds__(256) void flash_k(const float* __restrict__ Q,
                                               const float* __restrict__ Kg,
                                               const float* __restrict__ V,
                                               float* __restrict__ O) {
  const int qb = (int)gridDim.x - 1 - (int)blockIdx.x;  // heavy tiles first
  const int bh = blockIdx.y;
  const int b = bh >> 4, h = bh & 15;
  const int q0 = qb << 6;
  __shared__ __align__(16) float Qs[4096];
  __shared__ __align__(16) float Ks[4096];
  __shared__ __align__(16) float Vs[4096];
  __shared__ __align__(16) float Ss[64][68];
  const int tid = threadIdx.x;
  const int r0 = (tid >> 4) << 2;
  const int c0 = (tid & 15) << 2;
  const long base_q = ((long)bh * 2048 + q0) * 64;
#pragma unroll
  for (int rep = 0; rep < 4; ++rep) {
    const int f = tid + rep * 256;
    const int r = f >> 4;
    const int c4 = (f & 15) << 2;
    *(float4*)&Qs[SWZ(r, c4)] = *(const float4*)(Q + base_q + r * 64 + c4);
  }
  float m_st[4], l_st[4];
#pragma unroll
  for (int i = 0; i < 4; ++i) { m_st[i] = -3.0e38f; l_st[i] = 0.f; }
  float o_acc[4][4] = {};
  for (int kb = 0; kb <= qb; ++kb) {
    const long base_k = ((long)bh * 2048 + (kb << 6)) * 64;
    __syncthreads();
#pragma unroll
    for (int rep = 0; rep < 4; ++rep) {
      const int f = tid + rep * 256;
      const int r = f >> 4;
      const int c4 = (f & 15) << 2;
      *(float4*)&Ks[SWZ(r, c4)] = *(const float4*)(Kg + base_k + r * 64 + c4);
      *(float4*)&Vs[SWZ(r, c4)] = *(const float4*)(V + base_k + r * 64 + c4);
    }
    __syncthreads();
    float s[4][4] = {};
#pragma unroll
    for (int dq = 0; dq < 16; ++dq) {
      float4 qv[4], kv[4];
#pragma unroll
      for (int i = 0; i < 4; ++i) qv[i] = *(const float4*)&Qs[SWZ(r0 + i, dq << 2)];
#pragma unroll
      for (int j = 0; j < 4; ++j) kv[j] = *(const float4*)&Ks[SWZ(c0 + j, dq << 2)];
#pragma unroll
      for (int i = 0; i < 4; ++i)
#pragma unroll
        for (int j = 0; j < 4; ++j)
          s[i][j] += qv[i].x * kv[j].x + qv[i].y * kv[j].y +
                     qv[i].z * kv[j].z + qv[i].w * kv[j].w;
    }
    const bool diag = (kb == qb);
#pragma unroll
    for (int i = 0; i < 4; ++i) {
      float sr[4];
#pragma unroll
      for (int j = 0; j < 4; ++j) {
        float v = s[i][j] * 0.125f;
        if (diag && (c0 + j) > (r0 + i)) v = -1.0e30f;
        sr[j] = v;
      }
      float mt = fmaxf(fmaxf(sr[0], sr[1]), fmaxf(sr[2], sr[3]));
#pragma unroll
      for (int off = 1; off < 16; off <<= 1) mt = fmaxf(mt, __shfl_xor(mt, off));
      const float mn = fmaxf(m_st[i], mt);
      const float al = expf(m_st[i] - mn);
      float ps = 0.f;
#pragma unroll
      for (int j = 0; j < 4; ++j) { sr[j] = expf(sr[j] - mn); ps += sr[j]; }
#pragma unroll
      for (int off = 1; off < 16; off <<= 1) ps += __shfl_xor(ps, off);
      m_st[i] = mn;
      l_st[i] = l_st[i] * al + ps;
#pragma unroll
      for (int j = 0; j < 4; ++j) o_acc[i][j] *= al;
      *(float4*)&Ss[r0 + i][c0] = make_float4(sr[0], sr[1], sr[2], sr[3]);
    }
    // PV: Ss rows r0..r0+3 are wave-private (written+read by same wave)
#pragma unroll 4
    for (int kt = 0; kt < 16; ++kt) {
      float4 pr[4];
#pragma unroll
      for (int i = 0; i < 4; ++i) pr[i] = *(const float4*)&Ss[r0 + i][kt << 2];
      const float4 v0 = *(const float4*)&Vs[SWZ((kt << 2) + 0, c0)];
      const float4 v1 = *(const float4*)&Vs[SWZ((kt << 2) + 1, c0)];
      const float4 v2 = *(const float4*)&Vs[SWZ((kt << 2) + 2, c0)];
      const float4 v3 = *(const float4*)&Vs[SWZ((kt << 2) + 3, c0)];
#pragma unroll
      for (int i = 0; i < 4; ++i) {
        o_acc[i][0] = fmaf(pr[i].x, v0.x, fmaf(pr[i].y, v1.x, fmaf(pr[i].z, v2.x, fmaf(pr[i].w, v3.x, o_acc[i][0]))));
        o_acc[i][1] = fmaf(pr[i].x, v0.y, fmaf(pr[i].y, v1.y, fmaf(pr[i].z, v2.y, fmaf(pr[i].w, v3.y, o_acc[i][1]))));
        o_acc[i][2] = fmaf(pr[i].x, v0.z, fmaf(pr[i].y, v1.z, fmaf(pr[i].z, v2.z, fmaf(pr[i].w, v3.z, o_acc[i][2]))));
        o_acc[i][3] = fmaf(pr[i].x, v0.w, fmaf(pr[i].y, v1.w, fmaf(pr[i].z, v2.w, fmaf(pr[i].w, v3.w, o_acc[i][3]))));
      }
    }
  }
#pragma unroll
  for (int i = 0; i < 4; ++i) {
    const float il = 1.f / l_st[i];
    float4 ov = make_float4(o_acc[i][0] * il, o_acc[i][1] * il,
                            o_acc[i][2] * il, o_acc[i][3] * il);
    *(float4*)(O + ((long)(b * 2048 + q0 + r0 + i)) * 1024 + h * 64 + c0) = ov;
  }
}

// ---------------- Router ----------------
__global__ __launch_bounds__(256) void router_k(const float* __restrict__ xn,
                                                const float* __restrict__ rw,
                                                int* __restrict__ topi,
                                                float* __restrict__ topw,
                                                float* __restrict__ cnt,
                                                float* __restrict__ psum) {
  const int n = blockIdx.x;
  const int e = threadIdx.x >> 4;
  const int t = threadIdx.x & 15;
  float s = 0.f;
  const float* xr = xn + (long)n * 1024;
  const float* wr = rw + (long)e * 1024;
  for (int j = 0; j < 64; ++j) {
    const int d = t + (j << 4);
    s += xr[d] * wr[d];
  }
  __shared__ float part[16][17];
  part[e][t] = s;
  __syncthreads();
  if (threadIdx.x == 0) {
    float logits[16];
    for (int ee = 0; ee < 16; ++ee) {
      float acc = 0.f;
      for (int j = 0; j < 16; ++j) acc += part[ee][j];
      logits[ee] = acc;
    }
    float mx = logits[0];
    for (int ee = 1; ee < 16; ++ee) mx = fmaxf(mx, logits[ee]);
    float p[16];
    float Z = 0.f;
    for (int ee = 0; ee < 16; ++ee) { p[ee] = expf(logits[ee] - mx); Z += p[ee]; }
    const float iz = 1.f / Z;
    for (int ee = 0; ee < 16; ++ee) p[ee] *= iz;
    int i1 = 0;
    for (int ee = 1; ee < 16; ++ee) if (p[ee] > p[i1]) i1 = ee;
    int i2 = (i1 == 0) ? 1 : 0;
    for (int ee = 0; ee < 16; ++ee) if (ee != i1 && p[ee] > p[i2]) i2 = ee;
    const float sw = p[i1] + p[i2];
    topi[2 * n] = i1; topi[2 * n + 1] = i2;
    topw[2 * n] = p[i1] / sw; topw[2 * n + 1] = p[i2] / sw;
    atomicAdd(&cnt[i1], 1.f);
    atomicAdd(&cnt[i2], 1.f);
    for (int ee = 0; ee < 16; ++ee) atomicAdd(&psum[ee], p[ee]);
  }
}

// ---------------- Capacity scan + slot->token map ----------------
__global__ __launch_bounds__(256) void pos_k(const int* __restrict__ topi,
                                             const float* __restrict__ topw,
                                             int* __restrict__ slot,
                                             int* __restrict__ keep,
                                             int* __restrict__ s2t,
                                             float* __restrict__ s2w) {
  __shared__ int fi[8192];
  for (int i = threadIdx.x; i < 8192; i += 256) fi[i] = topi[i];
  __syncthreads();
  const int e = threadIdx.x;
  if (e < 16) {
    int count = 0;
    for (int i = 0; i < 8192; ++i) {
      if (fi[i] == e) {
        if (count < 640) {
          slot[i] = count; keep[i] = 1;
          s2t[e * 640 + count] = i >> 1;
          s2w[e * 640 + count] = topw[i];
        } else {
          slot[i] = 639; keep[i] = 0;
        }
        ++count;
      }
    }
    for (int c = (count < 640 ? count : 640); c < 640; ++c) s2t[e * 640 + c] = -1;
  }
}

__global__ __launch_bounds__(128) void scatter_b_k(const unsigned short* __restrict__ xnb,
                                                   const int* __restrict__ topi,
                                                   const int* __restrict__ slot,
                                                   const int* __restrict__ keep,
                                                   unsigned short* __restrict__ buf) {
  const int i = blockIdx.x;
  if (!keep[i]) return;
  const int n = i >> 1;
  const size_t dst = ((size_t)topi[i] * 640 + slot[i]) * 1024;
  ((uint4*)(buf + dst))[threadIdx.x] = ((const uint4*)(xnb + (size_t)n * 1024))[threadIdx.x];
}

__global__ void aux_k(const float* __restrict__ cnt, const float* __restrict__ psum,
                      float* __restrict__ out) {
  if (threadIdx.x == 0) {
    float s = 0.f;
    for (int e = 0; e < 16; ++e)
      s += (cnt[e] * (1.f / 4096.f)) * (psum[e] * (1.f / 4096.f));
    out[0] = 16.f * s;
  }
}

// ---------------- tou softmax (fp32 in -> bf16 probs) + gate ----------------
__global__ __launch_bounds__(256) void softmax512_k(const float* __restrict__ sc,
                                                    unsigned short* __restrict__ out) {
  const long n = blockIdx.x;
  const float2* row = (const float2*)(sc + n * 512);
  const int t = threadIdx.x;
  float2 v = row[t];
  float mx = fmaxf(v.x, v.y);
#pragma unroll
  for (int o = 32; o > 0; o >>= 1) mx = fmaxf(mx, __shfl_down(mx, o));
  __shared__ float red[4];
  __shared__ float bm, bz;
  if ((t & 63) == 0) red[t >> 6] = mx;
  __syncthreads();
  if (t == 0) bm = fmaxf(fmaxf(red[0], red[1]), fmaxf(red[2], red[3]));
  __syncthreads();
  const float M = bm;
  const float e0 = expf(v.x - M), e1 = expf(v.y - M);
  float s = e0 + e1;
#pragma unroll
  for (int o = 32; o > 0; o >>= 1) s += __shfl_down(s, o);
  if ((t & 63) == 0) red[t >> 6] = s;
  __syncthreads();
  if (t == 0) bz = 1.f / (red[0] + red[1] + red[2] + red[3]);
  __syncthreads();
  ushort2 u; u.x = f2bf(e0 * bz); u.y = f2bf(e1 * bz);
  *(ushort2*)(out + n * 512 + t * 2) = u;
}

__global__ __launch_bounds__(256) void gate_k(const float* __restrict__ xn,
                                              const float* __restrict__ gw,
                                              const float* __restrict__ gb,
                                              float* __restrict__ gate) {
  const long n = blockIdx.x;
  const int t = threadIdx.x;
  const float4 v = ((const float4*)(xn + n * 1024))[t];
  const float4 g = ((const float4*)gw)[t];
  float s = v.x * g.x + v.y * g.y + v.z * g.z + v.w * g.w;
#pragma unroll
  for (int o = 32; o > 0; o >>= 1) s += __shfl_down(s, o);
  __shared__ float red[4];
  if ((t & 63) == 0) red[t >> 6] = s;
  __syncthreads();
  if (t == 0) {
    const float tot = red[0] + red[1] + red[2] + red[3] + gb[0];
    gate[n] = 1.f / (1.f + expf(-tot));
  }
}

extern "C" void kernel_launch(void* const* d_in, const int* in_sizes, int n_in,
                              void* d_out, int out_size, void* d_ws, size_t ws_size,
                              hipStream_t stream) {
  (void)in_sizes; (void)n_in; (void)out_size; (void)ws_size;
  const float* x    = (const float*)d_in[0];
  const float* prim = (const float*)d_in[1];
  const float* n1w  = (const float*)d_in[2];
  const float* qkvw = (const float*)d_in[3];
  const float* aow  = (const float*)d_in[4];
  const float* n2w  = (const float*)d_in[5];
  const float* rw   = (const float*)d_in[6];
  const float* w1   = (const float*)d_in[7];
  const float* w2   = (const float*)d_in[8];
  const float* n3w  = (const float*)d_in[9];
  const float* tqw  = (const float*)d_in[10];
  const float* tkw  = (const float*)d_in[11];
  const float* tvw  = (const float*)d_in[12];
  const float* tow  = (const float*)d_in[13];
  const float* tgw  = (const float*)d_in[14];
  const float* tgb  = (const float*)d_in[15];

  float* xbuf = (float*)d_out;
  float* aux  = xbuf + 4194304;

  char* W = (char*)d_ws;
  float* xn            = (float*)W;                      // 16 MB
  unsigned short* xnb  = (unsigned short*)(W + (16u << 20));  // 8 MB (= hi split)
  unsigned short* xnl  = (unsigned short*)(W + (24u << 20));  // 8 MB (lo split)
  char* P = W + (32u << 20);

  // phase A
  float* qkv           = (float*)P;                          // 48 MB
  float* qr            = (float*)(P + (48u << 20));
  float* kr            = (float*)(P + (64u << 20));
  float* vr            = (float*)(P + (80u << 20));
  float* attnx         = (float*)(P + (96u << 20));          // 16 MB
  unsigned short* axh  = (unsigned short*)(P + (112u << 20));
  unsigned short* axl  = (unsigned short*)(P + (120u << 20));
  unsigned short* qwh  = (unsigned short*)(P + (128u << 20));
  unsigned short* qwl  = (unsigned short*)(P + (134u << 20));
  unsigned short* aoh  = (unsigned short*)(P + (140u << 20));
  unsigned short* aol  = (unsigned short*)(P + (142u << 20));
  // phase B (aliases phase A)
  int*   topi = (int*)P;
  float* topw = (float*)(P + 65536);
  int*   slot = (int*)(P + 131072);
  int*   keep = (int*)(P + 196608);
  float* cnt  = (float*)(P + 262144);
  float* psum = (float*)(P + 262144 + 4096);
  int*   s2t  = (int*)(P + 327680);
  float* s2w  = (float*)(P + 393216);
  unsigned short* bufb = (unsigned short*)(P + (1u << 20));   // 21 MB
  unsigned short* hb   = (unsigned short*)(P + (22u << 20));  // 42 MB
  unsigned short* Wt   = (unsigned short*)(P + (64u << 20));  // 67 MB (w1t then w2t)
  // phase C (aliases again)
  unsigned short* tqb  = (unsigned short*)P;
  unsigned short* tkb  = (unsigned short*)(P + (2u << 20));
  unsigned short* tvtb = (unsigned short*)(P + (3u << 20));
  float*          tsc  = (float*)(P + (4u << 20));
  unsigned short* tpb  = (unsigned short*)(P + (12u << 20));
  unsigned short* tavb = (unsigned short*)(P + (16u << 20));
  float*          gate = (float*)(P + (18u << 20));
  unsigned short* tqwb = (unsigned short*)(P + (19u << 20));
  unsigned short* tkwb = (unsigned short*)(P + (20u << 20));
  unsigned short* tvwb = (unsigned short*)(P + (21u << 20));
  unsigned short* towb = (unsigned short*)(P + (22u << 20));
  unsigned short* primb= (unsigned short*)(P + (23u << 20));

  // ---- phase A: x += rope_attention(rmsnorm(x)) ----
  hipMemcpyAsync(xbuf, x, (size_t)4194304 * 4, hipMemcpyDeviceToDevice, stream);
  rmsnorm_k<<<4096, 256, 0, stream>>>(xbuf, n1w, xn, xnb);
  split_k<<<4096, 256, 0, stream>>>(xn, xnb, xnl, 1048576);
  split_k<<<3072, 256, 0, stream>>>(qkvw, qwh, qwl, 786432);
  split_k<<<1024, 256, 0, stream>>>(aow, aoh, aol, 262144);
  bgemm<0><<<dim3(24, 32, 1), 256, 0, stream>>>(xnb, qwh, qkv, 4096, 3072, 1024, 0, 0, 0, 1.f, nullptr, nullptr, nullptr);
  bgemm<1><<<dim3(24, 32, 1), 256, 0, stream>>>(xnb, qwl, qkv, 4096, 3072, 1024, 0, 0, 0, 1.f, nullptr, nullptr, nullptr);
  bgemm<1><<<dim3(24, 32, 1), 256, 0, stream>>>(xnl, qwh, qkv, 4096, 3072, 1024, 0, 0, 0, 1.f, nullptr, nullptr, nullptr);
  rope_split_k<<<4096, 256, 0, stream>>>(qkv, qr, kr, vr);
  flash_k<<<dim3(32, 32), 256, 0, stream>>>(qr, kr, vr, attnx);
  split_k<<<4096, 256, 0, stream>>>(attnx, axh, axl, 1048576);
  bgemm<1><<<dim3(8, 32, 1), 256, 0, stream>>>(axh, aoh, xbuf, 4096, 1024, 1024, 0, 0, 0, 1.f, nullptr, nullptr, nullptr);
  bgemm<1><<<dim3(8, 32, 1), 256, 0, stream>>>(axh, aol, xbuf, 4096, 1024, 1024, 0, 0, 0, 1.f, nullptr, nullptr, nullptr);
  bgemm<1><<<dim3(8, 32, 1), 256, 0, stream>>>(axl, aoh, xbuf, 4096, 1024, 1024, 0, 0, 0, 1.f, nullptr, nullptr, nullptr);

  // ---- phase B: MoE ----
  rmsnorm_k<<<4096, 256, 0, stream>>>(xbuf, n2w, xn, xnb);
  hipMemsetAsync(cnt, 0, 8192, stream);
  router_k<<<4096, 256, 0, stream>>>(xn, rw, topi, topw, cnt, psum);
  pos_k<<<1, 256, 0, stream>>>(topi, topw, slot, keep, s2t, s2w);
  hipMemsetAsync(bufb, 0, (size_t)16 * 640 * 1024 * 2, stream);
  scatter_b_k<<<8192, 128, 0, stream>>>(xnb, topi, slot, keep, bufb);
  cvt_t_k<<<dim3(64, 32, 16), 256, 0, stream>>>(w1, Wt, 1024, 2048);
  bgemm<3><<<dim3(16, 5, 16), 256, 0, stream>>>(bufb, Wt, hb, 640, 2048, 1024,
      (long)640 * 1024, (long)2048 * 1024, (long)640 * 2048, 1.f, nullptr, nullptr, nullptr);
  cvt_t_k<<<dim3(32, 64, 16), 256, 0, stream>>>(w2, Wt, 2048, 1024);
  bgemm<5><<<dim3(8, 5, 16), 256, 0, stream>>>(hb, Wt, xbuf, 640, 1024, 2048,
      (long)640 * 2048, (long)1024 * 2048, 0, 1.f, nullptr, s2t, s2w);
  aux_k<<<1, 64, 0, stream>>>(cnt, psum, aux);

  // ---- phase C: tou cross-attn ----
  rmsnorm_k<<<4096, 256, 0, stream>>>(xbuf, n3w, xn, xnb);
  cvt_k<<<256, 256, 0, stream>>>(tqw, tqwb, 65536);
  cvt_k<<<64, 256, 0, stream>>>(tkw, tkwb, 16384);
  cvt_k<<<64, 256, 0, stream>>>(tvw, tvwb, 16384);
  cvt_k<<<256, 256, 0, stream>>>(tow, towb, 65536);
  cvt_k<<<128, 256, 0, stream>>>(prim, primb, 32768);
  bgemm<2><<<dim3(2, 32, 1), 256, 0, stream>>>(xnb, tqwb, tqb, 4096, 256, 1024, 0, 0, 0, 1.f, nullptr, nullptr, nullptr);
  bgemm<2><<<dim3(2, 4, 1), 256, 0, stream>>>(primb, tkwb, tkb, 512, 256, 256, 0, 0, 0, 1.f, nullptr, nullptr, nullptr);
  bgemm<2><<<dim3(4, 2, 1), 256, 0, stream>>>(tvwb, primb, tvtb, 256, 512, 256, 0, 0, 0, 1.f, nullptr, nullptr, nullptr);
  bgemm<0><<<dim3(4, 32, 1), 256, 0, stream>>>(tqb, tkb, tsc, 4096, 512, 256, 0, 0, 0, 0.0625f, nullptr, nullptr, nullptr);
  softmax512_k<<<4096, 256, 0, stream>>>(tsc, tpb);
  bgemm<2><<<dim3(2, 32, 1), 256, 0, stream>>>(tpb, tvtb, tavb, 4096, 256, 512, 0, 0, 0, 1.f, nullptr, nullptr, nullptr);
  gate_k<<<4096, 256, 0, stream>>>(xn, tgw, tgb, gate);
  bgemm<4><<<dim3(8, 32, 1), 256, 0, stream>>>(tavb, towb, xbuf, 4096, 1024, 256, 0, 0, 0, 1.f, gate, nullptr, nullptr);
}

// Round 4
// 2072.704 us; speedup vs baseline: 2.6296x; 1.6492x over previous
//
#include <hip/hip_runtime.h>
#include <math.h>

// B=2 T=2048 D=1024 H=16 DH=64 E=16 K=2 F=2048 CAP=640 DP=256 NPRIM=512
typedef short bf16x8 __attribute__((ext_vector_type(8)));
typedef float f32x4 __attribute__((ext_vector_type(4)));

__device__ __forceinline__ unsigned short f2bf(float f) {
  union { float f; unsigned u; } v; v.f = f;
  return (unsigned short)((v.u + 0x7fff + ((v.u >> 16) & 1)) >> 16);
}
__device__ __forceinline__ float bf2f(unsigned short h) {
  union { unsigned u; float f; } v; v.u = ((unsigned)h) << 16;
  return v.f;
}

// ---------------- RMSNorm: fp32 out + bf16 out ----------------
__global__ __launch_bounds__(256) void rmsnorm_k(const float* __restrict__ x,
                                                 const float* __restrict__ w,
                                                 float* __restrict__ y,
                                                 unsigned short* __restrict__ yb) {
  const long n = blockIdx.x;
  const int t = threadIdx.x;
  const float4 v = ((const float4*)(x + n * 1024))[t];
  float ss = v.x * v.x + v.y * v.y + v.z * v.z + v.w * v.w;
#pragma unroll
  for (int o = 32; o > 0; o >>= 1) ss += __shfl_down(ss, o);
  __shared__ float red[4];
  __shared__ float sc;
  if ((t & 63) == 0) red[t >> 6] = ss;
  __syncthreads();
  if (t == 0) sc = rsqrtf((red[0] + red[1] + red[2] + red[3]) * (1.0f / 1024.0f) + 1e-6f);
  __syncthreads();
  const float s = sc;
  const float4 wv = ((const float4*)w)[t];
  float4 o;
  o.x = v.x * s * wv.x; o.y = v.y * s * wv.y; o.z = v.z * s * wv.z; o.w = v.w * s * wv.w;
  ((float4*)(y + n * 1024))[t] = o;
  ushort4 u = make_ushort4(f2bf(o.x), f2bf(o.y), f2bf(o.z), f2bf(o.w));
  *(ushort4*)(yb + n * 1024 + t * 4) = u;
}

// ---------------- fp32 -> bf16 flat ----------------
__global__ __launch_bounds__(256) void cvt_k(const float* __restrict__ in,
                                             unsigned short* __restrict__ out, int n4) {
  const int i = blockIdx.x * 256 + threadIdx.x;
  if (i >= n4) return;
  const float4 v = ((const float4*)in)[i];
  ((ushort4*)out)[i] = make_ushort4(f2bf(v.x), f2bf(v.y), f2bf(v.z), f2bf(v.w));
}

// ---------------- fp32 -> (hi, lo) bf16 split ----------------
__global__ __launch_bounds__(256) void split_k(const float* __restrict__ in,
                                               unsigned short* __restrict__ hi,
                                               unsigned short* __restrict__ lo, int n4) {
  const int i = blockIdx.x * 256 + threadIdx.x;
  if (i >= n4) return;
  const float4 v = ((const float4*)in)[i];
  ushort4 h = make_ushort4(f2bf(v.x), f2bf(v.y), f2bf(v.z), f2bf(v.w));
  ushort4 l = make_ushort4(f2bf(v.x - bf2f(h.x)), f2bf(v.y - bf2f(h.y)),
                           f2bf(v.z - bf2f(h.z)), f2bf(v.w - bf2f(h.w)));
  ((ushort4*)hi)[i] = h;
  ((ushort4*)lo)[i] = l;
}

// ---------------- transpose-convert: (R,C) fp32 -> (C,R) bf16, batched ----------------
__global__ __launch_bounds__(256) void cvt_t_k(const float* __restrict__ in,
                                               unsigned short* __restrict__ out,
                                               int R, int C) {
  in += (size_t)blockIdx.z * R * C;
  out += (size_t)blockIdx.z * R * C;
  const int r0 = blockIdx.y * 32, c0 = blockIdx.x * 32;
  __shared__ float T[32][33];
  const int tid = threadIdx.x;
  const int li = tid >> 3;
  const int lj = (tid & 7) << 2;
  const float4 v = *(const float4*)(in + (size_t)(r0 + li) * C + c0 + lj);
  T[li][lj + 0] = v.x; T[li][lj + 1] = v.y; T[li][lj + 2] = v.z; T[li][lj + 3] = v.w;
  __syncthreads();
  ushort4 u = make_ushort4(f2bf(T[lj + 0][li]), f2bf(T[lj + 1][li]),
                           f2bf(T[lj + 2][li]), f2bf(T[lj + 3][li]));
  *(ushort4*)(out + (size_t)(c0 + li) * R + r0 + lj) = u;
}

// ---------------- bf16 MFMA GEMM: C(M,N) = alpha * A(M,K) x B(N,K)^T ----------------
// MODE: 0=f32 store, 1=f32 +=, 2=bf16 store, 3=bf16 silu store,
//       4=f32 += rowscale[row]*v, 5=f32 atomicAdd to rowmap token (MoE un-scatter)
template <int MODE>
__global__ __launch_bounds__(256) void bgemm(const unsigned short* __restrict__ A,
                                             const unsigned short* __restrict__ B,
                                             void* __restrict__ Cv,
                                             int M, int N, int K,
                                             long sA, long sB, long sC, float alpha,
                                             const float* __restrict__ rowscale,
                                             const int* __restrict__ rowmap,
                                             const float* __restrict__ roww) {
  __shared__ __align__(16) unsigned short As[128][40];
  __shared__ __align__(16) unsigned short Bs[128][40];
  const int tid = threadIdx.x;
  const int z = blockIdx.z;
  const unsigned short* Ag = A + (size_t)z * sA;
  const unsigned short* Bg = B + (size_t)z * sB;
  const int m0 = blockIdx.y * 128, n0 = blockIdx.x * 128;
  const int lane = tid & 63;
  const int wid = tid >> 6;
  const int wm = (wid >> 1) * 64, wn = (wid & 1) * 64;
  const int fr = lane & 15, fq = lane >> 4;
  const int lr = tid >> 2, lk = (tid & 3) * 8;
  f32x4 acc[4][4] = {};
  const unsigned short* Ap0 = Ag + (size_t)(m0 + lr) * K + lk;
  const unsigned short* Ap1 = Ag + (size_t)(m0 + lr + 64) * K + lk;
  const unsigned short* Bp0 = Bg + (size_t)(n0 + lr) * K + lk;
  const unsigned short* Bp1 = Bg + (size_t)(n0 + lr + 64) * K + lk;
  uint4 a0 = *(const uint4*)Ap0, a1 = *(const uint4*)Ap1;
  uint4 b0 = *(const uint4*)Bp0, b1 = *(const uint4*)Bp1;
  for (int k0 = 0;;) {
    __syncthreads();
    *(uint4*)&As[lr][lk] = a0; *(uint4*)&As[lr + 64][lk] = a1;
    *(uint4*)&Bs[lr][lk] = b0; *(uint4*)&Bs[lr + 64][lk] = b1;
    __syncthreads();
    k0 += 32;
    if (k0 < K) {
      a0 = *(const uint4*)(Ap0 + k0); a1 = *(const uint4*)(Ap1 + k0);
      b0 = *(const uint4*)(Bp0 + k0); b1 = *(const uint4*)(Bp1 + k0);
    }
    bf16x8 af[4], bv[4];
#pragma unroll
    for (int i = 0; i < 4; ++i) af[i] = *(const bf16x8*)&As[wm + i * 16 + fr][fq * 8];
#pragma unroll
    for (int j = 0; j < 4; ++j) bv[j] = *(const bf16x8*)&Bs[wn + j * 16 + fr][fq * 8];
#pragma unroll
    for (int i = 0; i < 4; ++i)
#pragma unroll
      for (int j = 0; j < 4; ++j)
        acc[i][j] = __builtin_amdgcn_mfma_f32_16x16x32_bf16(af[i], bv[j], acc[i][j], 0, 0, 0);
    if (k0 >= K) break;
  }
#pragma unroll
  for (int i = 0; i < 4; ++i) {
#pragma unroll
    for (int reg = 0; reg < 4; ++reg) {
      const int row = m0 + wm + i * 16 + fq * 4 + reg;
      float rs = 0.f, wgt = 0.f;
      int tok = -1;
      if (MODE == 4) rs = rowscale[row];
      if (MODE == 5) {
        tok = rowmap[z * M + row];
        if (tok >= 0) wgt = roww[z * M + row];
      }
#pragma unroll
      for (int j = 0; j < 4; ++j) {
        const int col = n0 + wn + j * 16 + fr;
        const float v = alpha * acc[i][j][reg];
        if (MODE == 0) {
          ((float*)Cv + (size_t)z * sC)[(size_t)row * N + col] = v;
        } else if (MODE == 1) {
          float* p = (float*)Cv + (size_t)z * sC + (size_t)row * N + col;
          *p += v;
        } else if (MODE == 2) {
          ((unsigned short*)Cv + (size_t)z * sC)[(size_t)row * N + col] = f2bf(v);
        } else if (MODE == 3) {
          const float sv = v / (1.f + expf(-v));
          ((unsigned short*)Cv + (size_t)z * sC)[(size_t)row * N + col] = f2bf(sv);
        } else if (MODE == 4) {
          float* p = (float*)Cv + (size_t)row * N + col;
          *p += rs * v;
        } else if (MODE == 5) {
          if (tok >= 0) atomicAdd((float*)Cv + (size_t)tok * N + col, wgt * v);
        }
      }
    }
  }
}

// ---------------- Fused split-bf16 GEMM: C = (Ah+Al)(Bh+Bl)^T (3-term) ----------------
// MODE: 0 = f32 store, 1 = f32 +=
template <int MODE>
__global__ __launch_bounds__(256) void bgemm_s(const unsigned short* __restrict__ Ah,
                                               const unsigned short* __restrict__ Al,
                                               const unsigned short* __restrict__ Bh,
                                               const unsigned short* __restrict__ Bl,
                                               float* __restrict__ C,
                                               int M, int N, int K) {
  __shared__ __align__(16) unsigned short Ash[128][40];
  __shared__ __align__(16) unsigned short Asl[128][40];
  __shared__ __align__(16) unsigned short Bsh[128][40];
  __shared__ __align__(16) unsigned short Bsl[128][40];
  const int tid = threadIdx.x;
  const int m0 = blockIdx.y * 128, n0 = blockIdx.x * 128;
  const int lane = tid & 63;
  const int wid = tid >> 6;
  const int wm = (wid >> 1) * 64, wn = (wid & 1) * 64;
  const int fr = lane & 15, fq = lane >> 4;
  const int lr = tid >> 2, lk = (tid & 3) * 8;
  f32x4 acc[4][4] = {};
  const size_t oA0 = (size_t)(m0 + lr) * K + lk, oA1 = (size_t)(m0 + lr + 64) * K + lk;
  const size_t oB0 = (size_t)(n0 + lr) * K + lk, oB1 = (size_t)(n0 + lr + 64) * K + lk;
  uint4 ah0 = *(const uint4*)(Ah + oA0), ah1 = *(const uint4*)(Ah + oA1);
  uint4 al0 = *(const uint4*)(Al + oA0), al1 = *(const uint4*)(Al + oA1);
  uint4 bh0 = *(const uint4*)(Bh + oB0), bh1 = *(const uint4*)(Bh + oB1);
  uint4 bl0 = *(const uint4*)(Bl + oB0), bl1 = *(const uint4*)(Bl + oB1);
  for (int k0 = 0;;) {
    __syncthreads();
    *(uint4*)&Ash[lr][lk] = ah0; *(uint4*)&Ash[lr + 64][lk] = ah1;
    *(uint4*)&Asl[lr][lk] = al0; *(uint4*)&Asl[lr + 64][lk] = al1;
    *(uint4*)&Bsh[lr][lk] = bh0; *(uint4*)&Bsh[lr + 64][lk] = bh1;
    *(uint4*)&Bsl[lr][lk] = bl0; *(uint4*)&Bsl[lr + 64][lk] = bl1;
    __syncthreads();
    k0 += 32;
    if (k0 < K) {
      ah0 = *(const uint4*)(Ah + oA0 + k0); ah1 = *(const uint4*)(Ah + oA1 + k0);
      al0 = *(const uint4*)(Al + oA0 + k0); al1 = *(const uint4*)(Al + oA1 + k0);
      bh0 = *(const uint4*)(Bh + oB0 + k0); bh1 = *(const uint4*)(Bh + oB1 + k0);
      bl0 = *(const uint4*)(Bl + oB0 + k0); bl1 = *(const uint4*)(Bl + oB1 + k0);
    }
    bf16x8 afh[4], afl[4];
#pragma unroll
    for (int i = 0; i < 4; ++i) {
      afh[i] = *(const bf16x8*)&Ash[wm + i * 16 + fr][fq * 8];
      afl[i] = *(const bf16x8*)&Asl[wm + i * 16 + fr][fq * 8];
    }
#pragma unroll
    for (int j = 0; j < 4; ++j) {
      const bf16x8 bvh = *(const bf16x8*)&Bsh[wn + j * 16 + fr][fq * 8];
      const bf16x8 bvl = *(const bf16x8*)&Bsl[wn + j * 16 + fr][fq * 8];
#pragma unroll
      for (int i = 0; i < 4; ++i) {
        acc[i][j] = __builtin_amdgcn_mfma_f32_16x16x32_bf16(afl[i], bvh, acc[i][j], 0, 0, 0);
        acc[i][j] = __builtin_amdgcn_mfma_f32_16x16x32_bf16(afh[i], bvl, acc[i][j], 0, 0, 0);
        acc[i][j] = __builtin_amdgcn_mfma_f32_16x16x32_bf16(afh[i], bvh, acc[i][j], 0, 0, 0);
      }
    }
    if (k0 >= K) break;
  }
#pragma unroll
  for (int i = 0; i < 4; ++i) {
#pragma unroll
    for (int reg = 0; reg < 4; ++reg) {
      const int row = m0 + wm + i * 16 + fq * 4 + reg;
#pragma unroll
      for (int j = 0; j < 4; ++j) {
        const int col = n0 + wn + j * 16 + fr;
        float* p = C + (size_t)row * N + col;
        if (MODE == 0) *p = acc[i][j][reg];
        else *p += acc[i][j][reg];
      }
    }
  }
}

// ---------------- RoPE + hi/lo split/transpose to bf16 [bh][t][dh] ----------------
__global__ __launch_bounds__(256) void rope_split6_k(const float* __restrict__ qkv,
                                                     unsigned short* __restrict__ Qh,
                                                     unsigned short* __restrict__ Ql,
                                                     unsigned short* __restrict__ Kh,
                                                     unsigned short* __restrict__ Kl,
                                                     unsigned short* __restrict__ Vh,
                                                     unsigned short* __restrict__ Vl) {
  const int n = blockIdx.x;
  const int b = n >> 11;
  const int t = n & 2047;
  const float l2t = 13.287712379549449f;
  const float* row = qkv + (long)n * 3072;
  for (int idx = threadIdx.x; idx < 3072; idx += 256) {
    const int which = idx >> 10;
    const int rem = idx & 1023;
    const int h = rem >> 6;
    const int d = rem & 63;
    const float val = row[idx];
    float out;
    if (which == 2) {
      out = val;
    } else {
      const float inv = exp2f(-l2t * (float)(d & 31) * (1.0f / 32.0f));
      const float ang = (float)t * inv;
      const float c = cosf(ang), s = sinf(ang);
      const float other = (d < 32) ? -row[which * 1024 + h * 64 + d + 32]
                                   : row[which * 1024 + h * 64 + d - 32];
      out = val * c + other * s;
    }
    const long o = ((long)(b * 16 + h) * 2048 + t) * 64 + d;
    const unsigned short hi = f2bf(out);
    const unsigned short lo = f2bf(out - bf2f(hi));
    if (which == 0)      { Qh[o] = hi; Ql[o] = lo; }
    else if (which == 1) { Kh[o] = hi; Kl[o] = lo; }
    else                 { Vh[o] = hi; Vl[o] = lo; }
  }
}

// ---------------- Split-bf16 MFMA flash attention (router-safe precision) ----------------
// grid (32 qtiles, 32 bh), 256 thr = 4 waves; wave w: q-rows [w*16, w*16+16)
__global__ __launch_bounds__(256) void flash_k(const unsigned short* __restrict__ Qhg,
                                               const unsigned short* __restrict__ Qlg,
                                               const unsigned short* __restrict__ Khg,
                                               const unsigned short* __restrict__ Klg,
                                               const unsigned short* __restrict__ Vhg,
                                               const unsigned short* __restrict__ Vlg,
                                               unsigned short* __restrict__ axh,
                                               unsigned short* __restrict__ axl) {
  const int qb = (int)gridDim.x - 1 - (int)blockIdx.x;  // heavy tiles first
  const int bh = blockIdx.y;
  const int b = bh >> 4, h = bh & 15;
  const int q0 = qb << 6;
  __shared__ __align__(16) unsigned short Qsh[64][72];
  __shared__ __align__(16) unsigned short Qsl[64][72];
  __shared__ __align__(16) unsigned short Ksh[64][72];
  __shared__ __align__(16) unsigned short Ksl[64][72];
  __shared__ __align__(16) unsigned short Vth[64][72];  // [d][t]
  __shared__ __align__(16) unsigned short Vtl[64][72];
  __shared__ __align__(16) unsigned short Psh[4][16][72];
  __shared__ __align__(16) unsigned short Psl[4][16][72];
  const int tid = threadIdx.x;
  const int w = tid >> 6;
  const int lane = tid & 63;
  const int fr = lane & 15, fq = lane >> 4;
  const long base_q = ((long)bh * 2048 + q0) * 64;
#pragma unroll
  for (int rep = 0; rep < 2; ++rep) {
    const int f = tid + rep * 256;
    const int r = f >> 3, c8 = (f & 7) * 8;
    *(uint4*)&Qsh[r][c8] = *(const uint4*)(Qhg + base_q + r * 64 + c8);
    *(uint4*)&Qsl[r][c8] = *(const uint4*)(Qlg + base_q + r * 64 + c8);
  }
  f32x4 o_acc[4] = {};
  float m_st[4], l_st[4];
#pragma unroll
  for (int i = 0; i < 4; ++i) { m_st[i] = -3.0e38f; l_st[i] = 0.f; }
  for (int kb = 0; kb <= qb; ++kb) {
    const long base_k = ((long)bh * 2048 + (kb << 6)) * 64;
    __syncthreads();
#pragma unroll
    for (int rep = 0; rep < 2; ++rep) {
      const int f = tid + rep * 256;
      const int r = f >> 3, c8 = (f & 7) * 8;
      *(uint4*)&Ksh[r][c8] = *(const uint4*)(Khg + base_k + r * 64 + c8);
      *(uint4*)&Ksl[r][c8] = *(const uint4*)(Klg + base_k + r * 64 + c8);
    }
#pragma unroll
    for (int rep = 0; rep < 4; ++rep) {
      const int f = tid + rep * 256;
      const int tt = f >> 4, d0 = (f & 15) * 4;
      const ushort4 vh4 = *(const ushort4*)(Vhg + base_k + tt * 64 + d0);
      Vth[d0 + 0][tt] = vh4.x; Vth[d0 + 1][tt] = vh4.y;
      Vth[d0 + 2][tt] = vh4.z; Vth[d0 + 3][tt] = vh4.w;
      const ushort4 vl4 = *(const ushort4*)(Vlg + base_k + tt * 64 + d0);
      Vtl[d0 + 0][tt] = vl4.x; Vtl[d0 + 1][tt] = vl4.y;
      Vtl[d0 + 2][tt] = vl4.z; Vtl[d0 + 3][tt] = vl4.w;
    }
    __syncthreads();
    // S = Q K^T (3-term split): qh*kh + qh*kl + ql*kh
    f32x4 sfr[4] = {};
#pragma unroll
    for (int kc = 0; kc < 2; ++kc) {
      const bf16x8 qh_ = *(const bf16x8*)&Qsh[w * 16 + fr][kc * 32 + fq * 8];
      const bf16x8 ql_ = *(const bf16x8*)&Qsl[w * 16 + fr][kc * 32 + fq * 8];
#pragma unroll
      for (int j = 0; j < 4; ++j) {
        const bf16x8 kh_ = *(const bf16x8*)&Ksh[j * 16 + fr][kc * 32 + fq * 8];
        const bf16x8 kl_ = *(const bf16x8*)&Ksl[j * 16 + fr][kc * 32 + fq * 8];
        sfr[j] = __builtin_amdgcn_mfma_f32_16x16x32_bf16(ql_, kh_, sfr[j], 0, 0, 0);
        sfr[j] = __builtin_amdgcn_mfma_f32_16x16x32_bf16(qh_, kl_, sfr[j], 0, 0, 0);
        sfr[j] = __builtin_amdgcn_mfma_f32_16x16x32_bf16(qh_, kh_, sfr[j], 0, 0, 0);
      }
    }
    const bool diag = (kb == qb);
    float p[4][4];   // [j][reg]
    float alpha[4];
#pragma unroll
    for (int reg = 0; reg < 4; ++reg) {
      const int qloc = w * 16 + fq * 4 + reg;
      float v[4];
#pragma unroll
      for (int j = 0; j < 4; ++j) {
        float s = sfr[j][reg] * 0.125f;
        if (diag && (j * 16 + fr) > qloc) s = -1.0e30f;
        v[j] = s;
      }
      float mt = fmaxf(fmaxf(v[0], v[1]), fmaxf(v[2], v[3]));
#pragma unroll
      for (int off = 1; off < 16; off <<= 1) mt = fmaxf(mt, __shfl_xor(mt, off));
      const float mn = fmaxf(m_st[reg], mt);
      alpha[reg] = expf(m_st[reg] - mn);
      m_st[reg] = mn;
      float ps = 0.f;
#pragma unroll
      for (int j = 0; j < 4; ++j) { p[j][reg] = expf(v[j] - mn); ps += p[j][reg]; }
#pragma unroll
      for (int off = 1; off < 16; off <<= 1) ps += __shfl_xor(ps, off);
      l_st[reg] = l_st[reg] * alpha[reg] + ps;
    }
    // write P hi/lo (bf16) to wave-private LDS in A-operand layout
#pragma unroll
    for (int reg = 0; reg < 4; ++reg)
#pragma unroll
      for (int j = 0; j < 4; ++j) {
        const float pv = p[j][reg];
        const unsigned short ph = f2bf(pv);
        const unsigned short pl = f2bf(pv - bf2f(ph));
        Psh[w][fq * 4 + reg][j * 16 + fr] = ph;
        Psl[w][fq * 4 + reg][j * 16 + fr] = pl;
      }
    // rescale O
#pragma unroll
    for (int j = 0; j < 4; ++j)
#pragma unroll
      for (int reg = 0; reg < 4; ++reg) o_acc[j][reg] *= alpha[reg];
    // O += P V  (3-term split): ph*vh + ph*vl + pl*vh
#pragma unroll
    for (int kc = 0; kc < 2; ++kc) {
      const bf16x8 ph_ = *(const bf16x8*)&Psh[w][fr][kc * 32 + fq * 8];
      const bf16x8 pl_ = *(const bf16x8*)&Psl[w][fr][kc * 32 + fq * 8];
#pragma unroll
      for (int j = 0; j < 4; ++j) {
        const bf16x8 vh_ = *(const bf16x8*)&Vth[j * 16 + fr][kc * 32 + fq * 8];
        const bf16x8 vl_ = *(const bf16x8*)&Vtl[j * 16 + fr][kc * 32 + fq * 8];
        o_acc[j] = __builtin_amdgcn_mfma_f32_16x16x32_bf16(pl_, vh_, o_acc[j], 0, 0, 0);
        o_acc[j] = __builtin_amdgcn_mfma_f32_16x16x32_bf16(ph_, vl_, o_acc[j], 0, 0, 0);
        o_acc[j] = __builtin_amdgcn_mfma_f32_16x16x32_bf16(ph_, vh_, o_acc[j], 0, 0, 0);
      }
    }
  }
  // epilogue: divide by l, split hi/lo bf16, store
#pragma unroll
  for (int reg = 0; reg < 4; ++reg) {
    const long tok = (long)b * 2048 + q0 + w * 16 + fq * 4 + reg;
    const float il = 1.f / l_st[reg];
#pragma unroll
    for (int j = 0; j < 4; ++j) {
      const float v = o_acc[j][reg] * il;
      const unsigned short hi = f2bf(v);
      const unsigned short lo = f2bf(v - bf2f(hi));
      const long off = tok * 1024 + h * 64 + j * 16 + fr;
      axh[off] = hi;
      axl[off] = lo;
    }
  }
}

// ---------------- Router ----------------
__global__ __launch_bounds__(256) void router_k(const float* __restrict__ xn,
                                                const float* __restrict__ rw,
                                                int* __restrict__ topi,
                                                float* __restrict__ topw,
                                                float* __restrict__ cnt,
                                                float* __restrict__ psum) {
  const int n = blockIdx.x;
  const int e = threadIdx.x >> 4;
  const int t = threadIdx.x & 15;
  float s = 0.f;
  const float* xr = xn + (long)n * 1024;
  const float* wr = rw + (long)e * 1024;
  for (int j = 0; j < 64; ++j) {
    const int d = t + (j << 4);
    s += xr[d] * wr[d];
  }
  __shared__ float part[16][17];
  part[e][t] = s;
  __syncthreads();
  if (threadIdx.x == 0) {
    float logits[16];
    for (int ee = 0; ee < 16; ++ee) {
      float acc = 0.f;
      for (int j = 0; j < 16; ++j) acc += part[ee][j];
      logits[ee] = acc;
    }
    float mx = logits[0];
    for (int ee = 1; ee < 16; ++ee) mx = fmaxf(mx, logits[ee]);
    float p[16];
    float Z = 0.f;
    for (int ee = 0; ee < 16; ++ee) { p[ee] = expf(logits[ee] - mx); Z += p[ee]; }
    const float iz = 1.f / Z;
    for (int ee = 0; ee < 16; ++ee) p[ee] *= iz;
    int i1 = 0;
    for (int ee = 1; ee < 16; ++ee) if (p[ee] > p[i1]) i1 = ee;
    int i2 = (i1 == 0) ? 1 : 0;
    for (int ee = 0; ee < 16; ++ee) if (ee != i1 && p[ee] > p[i2]) i2 = ee;
    const float sw = p[i1] + p[i2];
    topi[2 * n] = i1; topi[2 * n + 1] = i2;
    topw[2 * n] = p[i1] / sw; topw[2 * n + 1] = p[i2] / sw;
    atomicAdd(&cnt[i1], 1.f);
    atomicAdd(&cnt[i2], 1.f);
    for (int ee = 0; ee < 16; ++ee) atomicAdd(&psum[ee], p[ee]);
  }
}

// ---------------- Parallel capacity scan (order-exact) ----------------
__global__ __launch_bounds__(256) void pos_k(const int* __restrict__ topi,
                                             const float* __restrict__ topw,
                                             int* __restrict__ slot,
                                             int* __restrict__ keep,
                                             int* __restrict__ s2t,
                                             float* __restrict__ s2w) {
  __shared__ int fi[8192];
  __shared__ int hist[256][16];
  __shared__ int total[16];
  const int t = threadIdx.x;
  for (int i = t; i < 8192; i += 256) fi[i] = topi[i];
#pragma unroll
  for (int e = 0; e < 16; ++e) hist[t][e] = 0;
  __syncthreads();
  const int base = t * 32;
#pragma unroll 8
  for (int i = 0; i < 32; ++i) hist[t][fi[base + i]]++;
  __syncthreads();
  if (t < 16) {
    int run = 0;
    for (int c = 0; c < 256; ++c) { const int v = hist[c][t]; hist[c][t] = run; run += v; }
    total[t] = run;
  }
  __syncthreads();
  int run[16];
#pragma unroll
  for (int e = 0; e < 16; ++e) run[e] = hist[t][e];
  for (int i = 0; i < 32; ++i) {
    const int idx = base + i;
    const int e = fi[idx];
    const int p = run[e]++;
    if (p < 640) {
      slot[idx] = p; keep[idx] = 1;
      s2t[e * 640 + p] = idx >> 1;
      s2w[e * 640 + p] = topw[idx];
    } else {
      slot[idx] = 639; keep[idx] = 0;
    }
  }
  __syncthreads();
  for (int pos = t; pos < 16 * 640; pos += 256) {
    const int e = pos / 640, c = pos - e * 640;
    if (c >= total[e]) s2t[pos] = -1;
  }
}

__global__ __launch_bounds__(128) void scatter_b_k(const unsigned short* __restrict__ xnb,
                                                   const int* __restrict__ topi,
                                                   const int* __restrict__ slot,
                                                   const int* __restrict__ keep,
                                                   unsigned short* __restrict__ buf) {
  const int i = blockIdx.x;
  if (!keep[i]) return;
  const int n = i >> 1;
  const size_t dst = ((size_t)topi[i] * 640 + slot[i]) * 1024;
  ((uint4*)(buf + dst))[threadIdx.x] = ((const uint4*)(xnb + (size_t)n * 1024))[threadIdx.x];
}

__global__ void aux_k(const float* __restrict__ cnt, const float* __restrict__ psum,
                      float* __restrict__ out) {
  if (threadIdx.x == 0) {
    float s = 0.f;
    for (int e = 0; e < 16; ++e)
      s += (cnt[e] * (1.f / 4096.f)) * (psum[e] * (1.f / 4096.f));
    out[0] = 16.f * s;
  }
}

// ---------------- tou softmax (fp32 in -> bf16 probs) + gate ----------------
__global__ __launch_bounds__(256) void softmax512_k(const float* __restrict__ sc,
                                                    unsigned short* __restrict__ out) {
  const long n = blockIdx.x;
  const float2* row = (const float2*)(sc + n * 512);
  const int t = threadIdx.x;
  float2 v = row[t];
  float mx = fmaxf(v.x, v.y);
#pragma unroll
  for (int o = 32; o > 0; o >>= 1) mx = fmaxf(mx, __shfl_down(mx, o));
  __shared__ float red[4];
  __shared__ float bm, bz;
  if ((t & 63) == 0) red[t >> 6] = mx;
  __syncthreads();
  if (t == 0) bm = fmaxf(fmaxf(red[0], red[1]), fmaxf(red[2], red[3]));
  __syncthreads();
  const float M = bm;
  const float e0 = expf(v.x - M), e1 = expf(v.y - M);
  float s = e0 + e1;
#pragma unroll
  for (int o = 32; o > 0; o >>= 1) s += __shfl_down(s, o);
  if ((t & 63) == 0) red[t >> 6] = s;
  __syncthreads();
  if (t == 0) bz = 1.f / (red[0] + red[1] + red[2] + red[3]);
  __syncthreads();
  ushort2 u; u.x = f2bf(e0 * bz); u.y = f2bf(e1 * bz);
  *(ushort2*)(out + n * 512 + t * 2) = u;
}

__global__ __launch_bounds__(256) void gate_k(const float* __restrict__ xn,
                                              const float* __restrict__ gw,
                                              const float* __restrict__ gb,
                                              float* __restrict__ gate) {
  const long n = blockIdx.x;
  const int t = threadIdx.x;
  const float4 v = ((const float4*)(xn + n * 1024))[t];
  const float4 g = ((const float4*)gw)[t];
  float s = v.x * g.x + v.y * g.y + v.z * g.z + v.w * g.w;
#pragma unroll
  for (int o = 32; o > 0; o >>= 1) s += __shfl_down(s, o);
  __shared__ float red[4];
  if ((t & 63) == 0) red[t >> 6] = s;
  __syncthreads();
  if (t == 0) {
    const float tot = red[0] + red[1] + red[2] + red[3] + gb[0];
    gate[n] = 1.f / (1.f + expf(-tot));
  }
}

extern "C" void kernel_launch(void* const* d_in, const int* in_sizes, int n_in,
                              void* d_out, int out_size, void* d_ws, size_t ws_size,
                              hipStream_t stream) {
  (void)in_sizes; (void)n_in; (void)out_size; (void)ws_size;
  const float* x    = (const float*)d_in[0];
  const float* prim = (const float*)d_in[1];
  const float* n1w  = (const float*)d_in[2];
  const float* qkvw = (const float*)d_in[3];
  const float* aow  = (const float*)d_in[4];
  const float* n2w  = (const float*)d_in[5];
  const float* rw   = (const float*)d_in[6];
  const float* w1   = (const float*)d_in[7];
  const float* w2   = (const float*)d_in[8];
  const float* n3w  = (const float*)d_in[9];
  const float* tqw  = (const float*)d_in[10];
  const float* tkw  = (const float*)d_in[11];
  const float* tvw  = (const float*)d_in[12];
  const float* tow  = (const float*)d_in[13];
  const float* tgw  = (const float*)d_in[14];
  const float* tgb  = (const float*)d_in[15];

  float* xbuf = (float*)d_out;
  float* aux  = xbuf + 4194304;

  char* W = (char*)d_ws;
  float* xn            = (float*)W;                           // 16 MB
  unsigned short* xnb  = (unsigned short*)(W + (16u << 20));  // 8 MB (hi)
  unsigned short* xnl  = (unsigned short*)(W + (24u << 20));  // 8 MB (lo)
  char* P = W + (32u << 20);

  // phase A
  float* qkv           = (float*)P;                           // 48 MB
  unsigned short* qh   = (unsigned short*)(P + (48u << 20));  // 8 MB each
  unsigned short* ql   = (unsigned short*)(P + (56u << 20));
  unsigned short* kh   = (unsigned short*)(P + (64u << 20));
  unsigned short* kl   = (unsigned short*)(P + (72u << 20));
  unsigned short* vh   = (unsigned short*)(P + (80u << 20));
  unsigned short* vl   = (unsigned short*)(P + (88u << 20));
  unsigned short* axh  = (unsigned short*)(P + (112u << 20));
  unsigned short* axl  = (unsigned short*)(P + (120u << 20));
  unsigned short* qwh  = (unsigned short*)(P + (128u << 20));
  unsigned short* qwl  = (unsigned short*)(P + (134u << 20));
  unsigned short* aoh  = (unsigned short*)(P + (140u << 20));
  unsigned short* aol  = (unsigned short*)(P + (142u << 20));
  // phase B (aliases phase A)
  int*   topi = (int*)P;
  float* topw = (float*)(P + 65536);
  int*   slot = (int*)(P + 131072);
  int*   keep = (int*)(P + 196608);
  float* cnt  = (float*)(P + 262144);
  float* psum = (float*)(P + 262144 + 4096);
  int*   s2t  = (int*)(P + 327680);
  float* s2w  = (float*)(P + 393216);
  unsigned short* bufb = (unsigned short*)(P + (1u << 20));   // 21 MB
  unsigned short* hb   = (unsigned short*)(P + (22u << 20));  // 42 MB
  unsigned short* Wt   = (unsigned short*)(P + (64u << 20));  // 67 MB
  // phase C (aliases again)
  unsigned short* tqb  = (unsigned short*)P;
  unsigned short* tkb  = (unsigned short*)(P + (2u << 20));
  unsigned short* tvtb = (unsigned short*)(P + (3u << 20));
  float*          tsc  = (float*)(P + (4u << 20));
  unsigned short* tpb  = (unsigned short*)(P + (12u << 20));
  unsigned short* tavb = (unsigned short*)(P + (16u << 20));
  float*          gate = (float*)(P + (18u << 20));
  unsigned short* tqwb = (unsigned short*)(P + (19u << 20));
  unsigned short* tkwb = (unsigned short*)(P + (20u << 20));
  unsigned short* tvwb = (unsigned short*)(P + (21u << 20));
  unsigned short* towb = (unsigned short*)(P + (22u << 20));
  unsigned short* primb= (unsigned short*)(P + (23u << 20));

  // ---- phase A: x += rope_attention(rmsnorm(x)) ----
  hipMemcpyAsync(xbuf, x, (size_t)4194304 * 4, hipMemcpyDeviceToDevice, stream);
  rmsnorm_k<<<4096, 256, 0, stream>>>(xbuf, n1w, xn, xnb);
  split_k<<<4096, 256, 0, stream>>>(xn, xnb, xnl, 1048576);
  split_k<<<3072, 256, 0, stream>>>(qkvw, qwh, qwl, 786432);
  split_k<<<1024, 256, 0, stream>>>(aow, aoh, aol, 262144);
  bgemm_s<0><<<dim3(24, 32, 1), 256, 0, stream>>>(xnb, xnl, qwh, qwl, qkv, 4096, 3072, 1024);
  rope_split6_k<<<4096, 256, 0, stream>>>(qkv, qh, ql, kh, kl, vh, vl);
  flash_k<<<dim3(32, 32), 256, 0, stream>>>(qh, ql, kh, kl, vh, vl, axh, axl);
  bgemm_s<1><<<dim3(8, 32, 1), 256, 0, stream>>>(axh, axl, aoh, aol, xbuf, 4096, 1024, 1024);

  // ---- phase B: MoE ----
  rmsnorm_k<<<4096, 256, 0, stream>>>(xbuf, n2w, xn, xnb);
  hipMemsetAsync(cnt, 0, 8192, stream);
  router_k<<<4096, 256, 0, stream>>>(xn, rw, topi, topw, cnt, psum);
  pos_k<<<1, 256, 0, stream>>>(topi, topw, slot, keep, s2t, s2w);
  hipMemsetAsync(bufb, 0, (size_t)16 * 640 * 1024 * 2, stream);
  scatter_b_k<<<8192, 128, 0, stream>>>(xnb, topi, slot, keep, bufb);
  cvt_t_k<<<dim3(64, 32, 16), 256, 0, stream>>>(w1, Wt, 1024, 2048);
  bgemm<3><<<dim3(16, 5, 16), 256, 0, stream>>>(bufb, Wt, hb, 640, 2048, 1024,
      (long)640 * 1024, (long)2048 * 1024, (long)640 * 2048, 1.f, nullptr, nullptr, nullptr);
  cvt_t_k<<<dim3(32, 64, 16), 256, 0, stream>>>(w2, Wt, 2048, 1024);
  bgemm<5><<<dim3(8, 5, 16), 256, 0, stream>>>(hb, Wt, xbuf, 640, 1024, 2048,
      (long)640 * 2048, (long)1024 * 2048, 0, 1.f, nullptr, s2t, s2w);
  aux_k<<<1, 64, 0, stream>>>(cnt, psum, aux);

  // ---- phase C: tou cross-attn ----
  rmsnorm_k<<<4096, 256, 0, stream>>>(xbuf, n3w, xn, xnb);
  cvt_k<<<256, 256, 0, stream>>>(tqw, tqwb, 65536);
  cvt_k<<<64, 256, 0, stream>>>(tkw, tkwb, 16384);
  cvt_k<<<64, 256, 0, stream>>>(tvw, tvwb, 16384);
  cvt_k<<<256, 256, 0, stream>>>(tow, towb, 65536);
  cvt_k<<<128, 256, 0, stream>>>(prim, primb, 32768);
  bgemm<2><<<dim3(2, 32, 1), 256, 0, stream>>>(xnb, tqwb, tqb, 4096, 256, 1024, 0, 0, 0, 1.f, nullptr, nullptr, nullptr);
  bgemm<2><<<dim3(2, 4, 1), 256, 0, stream>>>(primb, tkwb, tkb, 512, 256, 256, 0, 0, 0, 1.f, nullptr, nullptr, nullptr);
  bgemm<2><<<dim3(4, 2, 1), 256, 0, stream>>>(tvwb, primb, tvtb, 256, 512, 256, 0, 0, 0, 1.f, nullptr, nullptr, nullptr);
  bgemm<0><<<dim3(4, 32, 1), 256, 0, stream>>>(tqb, tkb, tsc, 4096, 512, 256, 0, 0, 0, 0.0625f, nullptr, nullptr, nullptr);
  softmax512_k<<<4096, 256, 0, stream>>>(tsc, tpb);
  bgemm<2><<<dim3(2, 32, 1), 256, 0, stream>>>(tpb, tvtb, tavb, 4096, 256, 512, 0, 0, 0, 1.f, nullptr, nullptr, nullptr);
  gate_k<<<4096, 256, 0, stream>>>(xn, tgw, tgb, gate);
  bgemm<4><<<dim3(8, 32, 1), 256, 0, stream>>>(tavb, towb, xbuf, 4096, 1024, 256, 0, 0, 0, 1.f, gate, nullptr, nullptr);
}

// Round 5
// 1260.804 us; speedup vs baseline: 4.3229x; 1.6440x over previous
//
#include <hip/hip_runtime.h>
#include <math.h>

// B=2 T=2048 D=1024 H=16 DH=64 E=16 K=2 F=2048 CAP=640 DP=256 NPRIM=512
typedef short bf16x8 __attribute__((ext_vector_type(8)));
typedef float f32x4 __attribute__((ext_vector_type(4)));

__device__ __forceinline__ unsigned short f2bf(float f) {
  union { float f; unsigned u; } v; v.f = f;
  return (unsigned short)((v.u + 0x7fff + ((v.u >> 16) & 1)) >> 16);
}
__device__ __forceinline__ float bf2f(unsigned short h) {
  union { unsigned u; float f; } v; v.u = ((unsigned)h) << 16;
  return v.f;
}

// ---------------- RMSNorm: fp32 out + bf16 out ----------------
__global__ __launch_bounds__(256) void rmsnorm_k(const float* __restrict__ x,
                                                 const float* __restrict__ w,
                                                 float* __restrict__ y,
                                                 unsigned short* __restrict__ yb) {
  const long n = blockIdx.x;
  const int t = threadIdx.x;
  const float4 v = ((const float4*)(x + n * 1024))[t];
  float ss = v.x * v.x + v.y * v.y + v.z * v.z + v.w * v.w;
#pragma unroll
  for (int o = 32; o > 0; o >>= 1) ss += __shfl_down(ss, o);
  __shared__ float red[4];
  __shared__ float sc;
  if ((t & 63) == 0) red[t >> 6] = ss;
  __syncthreads();
  if (t == 0) sc = rsqrtf((red[0] + red[1] + red[2] + red[3]) * (1.0f / 1024.0f) + 1e-6f);
  __syncthreads();
  const float s = sc;
  const float4 wv = ((const float4*)w)[t];
  float4 o;
  o.x = v.x * s * wv.x; o.y = v.y * s * wv.y; o.z = v.z * s * wv.z; o.w = v.w * s * wv.w;
  ((float4*)(y + n * 1024))[t] = o;
  ushort4 u = make_ushort4(f2bf(o.x), f2bf(o.y), f2bf(o.z), f2bf(o.w));
  *(ushort4*)(yb + n * 1024 + t * 4) = u;
}

// ---------------- fp32 -> bf16 flat ----------------
__global__ __launch_bounds__(256) void cvt_k(const float* __restrict__ in,
                                             unsigned short* __restrict__ out, int n4) {
  const int i = blockIdx.x * 256 + threadIdx.x;
  if (i >= n4) return;
  const float4 v = ((const float4*)in)[i];
  ((ushort4*)out)[i] = make_ushort4(f2bf(v.x), f2bf(v.y), f2bf(v.z), f2bf(v.w));
}

// ---------------- fp32 -> (hi, lo) bf16 split ----------------
__global__ __launch_bounds__(256) void split_k(const float* __restrict__ in,
                                               unsigned short* __restrict__ hi,
                                               unsigned short* __restrict__ lo, int n4) {
  const int i = blockIdx.x * 256 + threadIdx.x;
  if (i >= n4) return;
  const float4 v = ((const float4*)in)[i];
  ushort4 h = make_ushort4(f2bf(v.x), f2bf(v.y), f2bf(v.z), f2bf(v.w));
  ushort4 l = make_ushort4(f2bf(v.x - bf2f(h.x)), f2bf(v.y - bf2f(h.y)),
                           f2bf(v.z - bf2f(h.z)), f2bf(v.w - bf2f(h.w)));
  ((ushort4*)hi)[i] = h;
  ((ushort4*)lo)[i] = l;
}

// ---------------- transpose-convert: (R,C) fp32 -> (C,R) bf16, batched ----------------
__global__ __launch_bounds__(256) void cvt_t_k(const float* __restrict__ in,
                                               unsigned short* __restrict__ out,
                                               int R, int C) {
  in += (size_t)blockIdx.z * R * C;
  out += (size_t)blockIdx.z * R * C;
  const int r0 = blockIdx.y * 32, c0 = blockIdx.x * 32;
  __shared__ float T[32][33];
  const int tid = threadIdx.x;
  const int li = tid >> 3;
  const int lj = (tid & 7) << 2;
  const float4 v = *(const float4*)(in + (size_t)(r0 + li) * C + c0 + lj);
  T[li][lj + 0] = v.x; T[li][lj + 1] = v.y; T[li][lj + 2] = v.z; T[li][lj + 3] = v.w;
  __syncthreads();
  ushort4 u = make_ushort4(f2bf(T[lj + 0][li]), f2bf(T[lj + 1][li]),
                           f2bf(T[lj + 2][li]), f2bf(T[lj + 3][li]));
  *(ushort4*)(out + (size_t)(c0 + li) * R + r0 + lj) = u;
}

// ---------------- bf16 MFMA GEMM: C(M,N) = alpha * A(M,K) x B(N,K)^T ----------------
// MODE: 0=f32 store, 1=f32 +=, 2=bf16 store, 3=bf16 silu store,
//       4=f32 += rowscale[row]*v, 5=f32 atomicAdd to rowmap token (MoE un-scatter)
template <int MODE>
__global__ __launch_bounds__(256) void bgemm(const unsigned short* __restrict__ A,
                                             const unsigned short* __restrict__ B,
                                             void* __restrict__ Cv,
                                             int M, int N, int K,
                                             long sA, long sB, long sC, float alpha,
                                             const float* __restrict__ rowscale,
                                             const int* __restrict__ rowmap,
                                             const float* __restrict__ roww) {
  __shared__ __align__(16) unsigned short As[128][40];
  __shared__ __align__(16) unsigned short Bs[128][40];
  const int tid = threadIdx.x;
  const int z = blockIdx.z;
  const unsigned short* Ag = A + (size_t)z * sA;
  const unsigned short* Bg = B + (size_t)z * sB;
  const int m0 = blockIdx.y * 128, n0 = blockIdx.x * 128;
  const int lane = tid & 63;
  const int wid = tid >> 6;
  const int wm = (wid >> 1) * 64, wn = (wid & 1) * 64;
  const int fr = lane & 15, fq = lane >> 4;
  const int lr = tid >> 2, lk = (tid & 3) * 8;
  f32x4 acc[4][4] = {};
  const unsigned short* Ap0 = Ag + (size_t)(m0 + lr) * K + lk;
  const unsigned short* Ap1 = Ag + (size_t)(m0 + lr + 64) * K + lk;
  const unsigned short* Bp0 = Bg + (size_t)(n0 + lr) * K + lk;
  const unsigned short* Bp1 = Bg + (size_t)(n0 + lr + 64) * K + lk;
  uint4 a0 = *(const uint4*)Ap0, a1 = *(const uint4*)Ap1;
  uint4 b0 = *(const uint4*)Bp0, b1 = *(const uint4*)Bp1;
  for (int k0 = 0;;) {
    __syncthreads();
    *(uint4*)&As[lr][lk] = a0; *(uint4*)&As[lr + 64][lk] = a1;
    *(uint4*)&Bs[lr][lk] = b0; *(uint4*)&Bs[lr + 64][lk] = b1;
    __syncthreads();
    k0 += 32;
    if (k0 < K) {
      a0 = *(const uint4*)(Ap0 + k0); a1 = *(const uint4*)(Ap1 + k0);
      b0 = *(const uint4*)(Bp0 + k0); b1 = *(const uint4*)(Bp1 + k0);
    }
    bf16x8 af[4], bv[4];
#pragma unroll
    for (int i = 0; i < 4; ++i) af[i] = *(const bf16x8*)&As[wm + i * 16 + fr][fq * 8];
#pragma unroll
    for (int j = 0; j < 4; ++j) bv[j] = *(const bf16x8*)&Bs[wn + j * 16 + fr][fq * 8];
#pragma unroll
    for (int i = 0; i < 4; ++i)
#pragma unroll
      for (int j = 0; j < 4; ++j)
        acc[i][j] = __builtin_amdgcn_mfma_f32_16x16x32_bf16(af[i], bv[j], acc[i][j], 0, 0, 0);
    if (k0 >= K) break;
  }
#pragma unroll
  for (int i = 0; i < 4; ++i) {
#pragma unroll
    for (int reg = 0; reg < 4; ++reg) {
      const int row = m0 + wm + i * 16 + fq * 4 + reg;
      float rs = 0.f, wgt = 0.f;
      int tok = -1;
      if (MODE == 4) rs = rowscale[row];
      if (MODE == 5) {
        tok = rowmap[z * M + row];
        if (tok >= 0) wgt = roww[z * M + row];
      }
#pragma unroll
      for (int j = 0; j < 4; ++j) {
        const int col = n0 + wn + j * 16 + fr;
        const float v = alpha * acc[i][j][reg];
        if (MODE == 0) {
          ((float*)Cv + (size_t)z * sC)[(size_t)row * N + col] = v;
        } else if (MODE == 1) {
          float* p = (float*)Cv + (size_t)z * sC + (size_t)row * N + col;
          *p += v;
        } else if (MODE == 2) {
          ((unsigned short*)Cv + (size_t)z * sC)[(size_t)row * N + col] = f2bf(v);
        } else if (MODE == 3) {
          const float sv = v / (1.f + expf(-v));
          ((unsigned short*)Cv + (size_t)z * sC)[(size_t)row * N + col] = f2bf(sv);
        } else if (MODE == 4) {
          float* p = (float*)Cv + (size_t)row * N + col;
          *p += rs * v;
        } else if (MODE == 5) {
          if (tok >= 0) atomicAdd((float*)Cv + (size_t)tok * N + col, wgt * v);
        }
      }
    }
  }
}

// ---------------- Fused split-bf16 GEMM: C = (Ah+Al)(Bh+Bl)^T (3-term) ----------------
// MODE: 0 = f32 store, 1 = f32 +=
template <int MODE>
__global__ __launch_bounds__(256) void bgemm_s(const unsigned short* __restrict__ Ah,
                                               const unsigned short* __restrict__ Al,
                                               const unsigned short* __restrict__ Bh,
                                               const unsigned short* __restrict__ Bl,
                                               float* __restrict__ C,
                                               int M, int N, int K) {
  __shared__ __align__(16) unsigned short Ash[128][40];
  __shared__ __align__(16) unsigned short Asl[128][40];
  __shared__ __align__(16) unsigned short Bsh[128][40];
  __shared__ __align__(16) unsigned short Bsl[128][40];
  const int tid = threadIdx.x;
  const int m0 = blockIdx.y * 128, n0 = blockIdx.x * 128;
  const int lane = tid & 63;
  const int wid = tid >> 6;
  const int wm = (wid >> 1) * 64, wn = (wid & 1) * 64;
  const int fr = lane & 15, fq = lane >> 4;
  const int lr = tid >> 2, lk = (tid & 3) * 8;
  f32x4 acc[4][4] = {};
  const size_t oA0 = (size_t)(m0 + lr) * K + lk, oA1 = (size_t)(m0 + lr + 64) * K + lk;
  const size_t oB0 = (size_t)(n0 + lr) * K + lk, oB1 = (size_t)(n0 + lr + 64) * K + lk;
  uint4 ah0 = *(const uint4*)(Ah + oA0), ah1 = *(const uint4*)(Ah + oA1);
  uint4 al0 = *(const uint4*)(Al + oA0), al1 = *(const uint4*)(Al + oA1);
  uint4 bh0 = *(const uint4*)(Bh + oB0), bh1 = *(const uint4*)(Bh + oB1);
  uint4 bl0 = *(const uint4*)(Bl + oB0), bl1 = *(const uint4*)(Bl + oB1);
  for (int k0 = 0;;) {
    __syncthreads();
    *(uint4*)&Ash[lr][lk] = ah0; *(uint4*)&Ash[lr + 64][lk] = ah1;
    *(uint4*)&Asl[lr][lk] = al0; *(uint4*)&Asl[lr + 64][lk] = al1;
    *(uint4*)&Bsh[lr][lk] = bh0; *(uint4*)&Bsh[lr + 64][lk] = bh1;
    *(uint4*)&Bsl[lr][lk] = bl0; *(uint4*)&Bsl[lr + 64][lk] = bl1;
    __syncthreads();
    k0 += 32;
    if (k0 < K) {
      ah0 = *(const uint4*)(Ah + oA0 + k0); ah1 = *(const uint4*)(Ah + oA1 + k0);
      al0 = *(const uint4*)(Al + oA0 + k0); al1 = *(const uint4*)(Al + oA1 + k0);
      bh0 = *(const uint4*)(Bh + oB0 + k0); bh1 = *(const uint4*)(Bh + oB1 + k0);
      bl0 = *(const uint4*)(Bl + oB0 + k0); bl1 = *(const uint4*)(Bl + oB1 + k0);
    }
    bf16x8 afh[4], afl[4];
#pragma unroll
    for (int i = 0; i < 4; ++i) {
      afh[i] = *(const bf16x8*)&Ash[wm + i * 16 + fr][fq * 8];
      afl[i] = *(const bf16x8*)&Asl[wm + i * 16 + fr][fq * 8];
    }
#pragma unroll
    for (int j = 0; j < 4; ++j) {
      const bf16x8 bvh = *(const bf16x8*)&Bsh[wn + j * 16 + fr][fq * 8];
      const bf16x8 bvl = *(const bf16x8*)&Bsl[wn + j * 16 + fr][fq * 8];
#pragma unroll
      for (int i = 0; i < 4; ++i) {
        acc[i][j] = __builtin_amdgcn_mfma_f32_16x16x32_bf16(afl[i], bvh, acc[i][j], 0, 0, 0);
        acc[i][j] = __builtin_amdgcn_mfma_f32_16x16x32_bf16(afh[i], bvl, acc[i][j], 0, 0, 0);
        acc[i][j] = __builtin_amdgcn_mfma_f32_16x16x32_bf16(afh[i], bvh, acc[i][j], 0, 0, 0);
      }
    }
    if (k0 >= K) break;
  }
#pragma unroll
  for (int i = 0; i < 4; ++i) {
#pragma unroll
    for (int reg = 0; reg < 4; ++reg) {
      const int row = m0 + wm + i * 16 + fq * 4 + reg;
#pragma unroll
      for (int j = 0; j < 4; ++j) {
        const int col = n0 + wn + j * 16 + fr;
        float* p = C + (size_t)row * N + col;
        if (MODE == 0) *p = acc[i][j][reg];
        else *p += acc[i][j][reg];
      }
    }
  }
}

// ---------------- RoPE + hi/lo split/transpose to bf16 [bh][t][dh] ----------------
__global__ __launch_bounds__(256) void rope_split6_k(const float* __restrict__ qkv,
                                                     unsigned short* __restrict__ Qh,
                                                     unsigned short* __restrict__ Ql,
                                                     unsigned short* __restrict__ Kh,
                                                     unsigned short* __restrict__ Kl,
                                                     unsigned short* __restrict__ Vh,
                                                     unsigned short* __restrict__ Vl) {
  const int n = blockIdx.x;
  const int b = n >> 11;
  const int t = n & 2047;
  const float l2t = 13.287712379549449f;
  const float* row = qkv + (long)n * 3072;
  for (int idx = threadIdx.x; idx < 3072; idx += 256) {
    const int which = idx >> 10;
    const int rem = idx & 1023;
    const int h = rem >> 6;
    const int d = rem & 63;
    const float val = row[idx];
    float out;
    if (which == 2) {
      out = val;
    } else {
      const float inv = exp2f(-l2t * (float)(d & 31) * (1.0f / 32.0f));
      const float ang = (float)t * inv;
      const float c = cosf(ang), s = sinf(ang);
      const float other = (d < 32) ? -row[which * 1024 + h * 64 + d + 32]
                                   : row[which * 1024 + h * 64 + d - 32];
      out = val * c + other * s;
    }
    const long o = ((long)(b * 16 + h) * 2048 + t) * 64 + d;
    const unsigned short hi = f2bf(out);
    const unsigned short lo = f2bf(out - bf2f(hi));
    if (which == 0)      { Qh[o] = hi; Ql[o] = lo; }
    else if (which == 1) { Kh[o] = hi; Kl[o] = lo; }
    else                 { Vh[o] = hi; Vl[o] = lo; }
  }
}

// ---------------- Split-bf16 MFMA flash attention (router-safe precision) ----------------
__global__ __launch_bounds__(256) void flash_k(const unsigned short* __restrict__ Qhg,
                                               const unsigned short* __restrict__ Qlg,
                                               const unsigned short* __restrict__ Khg,
                                               const unsigned short* __restrict__ Klg,
                                               const unsigned short* __restrict__ Vhg,
                                               const unsigned short* __restrict__ Vlg,
                                               unsigned short* __restrict__ axh,
                                               unsigned short* __restrict__ axl) {
  const int qb = (int)gridDim.x - 1 - (int)blockIdx.x;  // heavy tiles first
  const int bh = blockIdx.y;
  const int b = bh >> 4, h = bh & 15;
  const int q0 = qb << 6;
  __shared__ __align__(16) unsigned short Qsh[64][72];
  __shared__ __align__(16) unsigned short Qsl[64][72];
  __shared__ __align__(16) unsigned short Ksh[64][72];
  __shared__ __align__(16) unsigned short Ksl[64][72];
  __shared__ __align__(16) unsigned short Vth[64][72];  // [d][t]
  __shared__ __align__(16) unsigned short Vtl[64][72];
  __shared__ __align__(16) unsigned short Psh[4][16][72];
  __shared__ __align__(16) unsigned short Psl[4][16][72];
  const int tid = threadIdx.x;
  const int w = tid >> 6;
  const int lane = tid & 63;
  const int fr = lane & 15, fq = lane >> 4;
  const long base_q = ((long)bh * 2048 + q0) * 64;
#pragma unroll
  for (int rep = 0; rep < 2; ++rep) {
    const int f = tid + rep * 256;
    const int r = f >> 3, c8 = (f & 7) * 8;
    *(uint4*)&Qsh[r][c8] = *(const uint4*)(Qhg + base_q + r * 64 + c8);
    *(uint4*)&Qsl[r][c8] = *(const uint4*)(Qlg + base_q + r * 64 + c8);
  }
  f32x4 o_acc[4] = {};
  float m_st[4], l_st[4];
#pragma unroll
  for (int i = 0; i < 4; ++i) { m_st[i] = -3.0e38f; l_st[i] = 0.f; }
  for (int kb = 0; kb <= qb; ++kb) {
    const long base_k = ((long)bh * 2048 + (kb << 6)) * 64;
    __syncthreads();
#pragma unroll
    for (int rep = 0; rep < 2; ++rep) {
      const int f = tid + rep * 256;
      const int r = f >> 3, c8 = (f & 7) * 8;
      *(uint4*)&Ksh[r][c8] = *(const uint4*)(Khg + base_k + r * 64 + c8);
      *(uint4*)&Ksl[r][c8] = *(const uint4*)(Klg + base_k + r * 64 + c8);
    }
#pragma unroll
    for (int rep = 0; rep < 4; ++rep) {
      const int f = tid + rep * 256;
      const int tt = f >> 4, d0 = (f & 15) * 4;
      const ushort4 vh4 = *(const ushort4*)(Vhg + base_k + tt * 64 + d0);
      Vth[d0 + 0][tt] = vh4.x; Vth[d0 + 1][tt] = vh4.y;
      Vth[d0 + 2][tt] = vh4.z; Vth[d0 + 3][tt] = vh4.w;
      const ushort4 vl4 = *(const ushort4*)(Vlg + base_k + tt * 64 + d0);
      Vtl[d0 + 0][tt] = vl4.x; Vtl[d0 + 1][tt] = vl4.y;
      Vtl[d0 + 2][tt] = vl4.z; Vtl[d0 + 3][tt] = vl4.w;
    }
    __syncthreads();
    f32x4 sfr[4] = {};
#pragma unroll
    for (int kc = 0; kc < 2; ++kc) {
      const bf16x8 qh_ = *(const bf16x8*)&Qsh[w * 16 + fr][kc * 32 + fq * 8];
      const bf16x8 ql_ = *(const bf16x8*)&Qsl[w * 16 + fr][kc * 32 + fq * 8];
#pragma unroll
      for (int j = 0; j < 4; ++j) {
        const bf16x8 kh_ = *(const bf16x8*)&Ksh[j * 16 + fr][kc * 32 + fq * 8];
        const bf16x8 kl_ = *(const bf16x8*)&Ksl[j * 16 + fr][kc * 32 + fq * 8];
        sfr[j] = __builtin_amdgcn_mfma_f32_16x16x32_bf16(ql_, kh_, sfr[j], 0, 0, 0);
        sfr[j] = __builtin_amdgcn_mfma_f32_16x16x32_bf16(qh_, kl_, sfr[j], 0, 0, 0);
        sfr[j] = __builtin_amdgcn_mfma_f32_16x16x32_bf16(qh_, kh_, sfr[j], 0, 0, 0);
      }
    }
    const bool diag = (kb == qb);
    float p[4][4];
    float alpha[4];
#pragma unroll
    for (int reg = 0; reg < 4; ++reg) {
      const int qloc = w * 16 + fq * 4 + reg;
      float v[4];
#pragma unroll
      for (int j = 0; j < 4; ++j) {
        float s = sfr[j][reg] * 0.125f;
        if (diag && (j * 16 + fr) > qloc) s = -1.0e30f;
        v[j] = s;
      }
      float mt = fmaxf(fmaxf(v[0], v[1]), fmaxf(v[2], v[3]));
#pragma unroll
      for (int off = 1; off < 16; off <<= 1) mt = fmaxf(mt, __shfl_xor(mt, off));
      const float mn = fmaxf(m_st[reg], mt);
      alpha[reg] = expf(m_st[reg] - mn);
      m_st[reg] = mn;
      float ps = 0.f;
#pragma unroll
      for (int j = 0; j < 4; ++j) { p[j][reg] = expf(v[j] - mn); ps += p[j][reg]; }
#pragma unroll
      for (int off = 1; off < 16; off <<= 1) ps += __shfl_xor(ps, off);
      l_st[reg] = l_st[reg] * alpha[reg] + ps;
    }
#pragma unroll
    for (int reg = 0; reg < 4; ++reg)
#pragma unroll
      for (int j = 0; j < 4; ++j) {
        const float pv = p[j][reg];
        const unsigned short ph = f2bf(pv);
        const unsigned short pl = f2bf(pv - bf2f(ph));
        Psh[w][fq * 4 + reg][j * 16 + fr] = ph;
        Psl[w][fq * 4 + reg][j * 16 + fr] = pl;
      }
#pragma unroll
    for (int j = 0; j < 4; ++j)
#pragma unroll
      for (int reg = 0; reg < 4; ++reg) o_acc[j][reg] *= alpha[reg];
#pragma unroll
    for (int kc = 0; kc < 2; ++kc) {
      const bf16x8 ph_ = *(const bf16x8*)&Psh[w][fr][kc * 32 + fq * 8];
      const bf16x8 pl_ = *(const bf16x8*)&Psl[w][fr][kc * 32 + fq * 8];
#pragma unroll
      for (int j = 0; j < 4; ++j) {
        const bf16x8 vh_ = *(const bf16x8*)&Vth[j * 16 + fr][kc * 32 + fq * 8];
        const bf16x8 vl_ = *(const bf16x8*)&Vtl[j * 16 + fr][kc * 32 + fq * 8];
        o_acc[j] = __builtin_amdgcn_mfma_f32_16x16x32_bf16(pl_, vh_, o_acc[j], 0, 0, 0);
        o_acc[j] = __builtin_amdgcn_mfma_f32_16x16x32_bf16(ph_, vl_, o_acc[j], 0, 0, 0);
        o_acc[j] = __builtin_amdgcn_mfma_f32_16x16x32_bf16(ph_, vh_, o_acc[j], 0, 0, 0);
      }
    }
  }
#pragma unroll
  for (int reg = 0; reg < 4; ++reg) {
    const long tok = (long)b * 2048 + q0 + w * 16 + fq * 4 + reg;
    const float il = 1.f / l_st[reg];
#pragma unroll
    for (int j = 0; j < 4; ++j) {
      const float v = o_acc[j][reg] * il;
      const unsigned short hi = f2bf(v);
      const unsigned short lo = f2bf(v - bf2f(hi));
      const long off = tok * 1024 + h * 64 + j * 16 + fr;
      axh[off] = hi;
      axl[off] = lo;
    }
  }
}

// ---------------- Router: coalesced dot, no atomics, probs to workspace ----------------
__global__ __launch_bounds__(256) void router_k(const float* __restrict__ xn,
                                                const float* __restrict__ rw,
                                                int* __restrict__ topi,
                                                float* __restrict__ topw,
                                                float* __restrict__ probs) {
  const int n = blockIdx.x;
  const int t = threadIdx.x;
  const float4 xv = ((const float4*)(xn + (size_t)n * 1024))[t];
  float acc[16];
#pragma unroll
  for (int e = 0; e < 16; ++e) {
    const float4 wv = ((const float4*)(rw + (size_t)e * 1024))[t];
    acc[e] = xv.x * wv.x + xv.y * wv.y + xv.z * wv.z + xv.w * wv.w;
  }
#pragma unroll
  for (int e = 0; e < 16; ++e)
#pragma unroll
    for (int o = 32; o > 0; o >>= 1) acc[e] += __shfl_down(acc[e], o);
  __shared__ float red[4][16];
  if ((t & 63) == 0) {
#pragma unroll
    for (int e = 0; e < 16; ++e) red[t >> 6][e] = acc[e];
  }
  __syncthreads();
  if (t == 0) {
    float logits[16];
#pragma unroll
    for (int e = 0; e < 16; ++e)
      logits[e] = red[0][e] + red[1][e] + red[2][e] + red[3][e];
    float mx = logits[0];
#pragma unroll
    for (int e = 1; e < 16; ++e) mx = fmaxf(mx, logits[e]);
    float p[16];
    float Z = 0.f;
#pragma unroll
    for (int e = 0; e < 16; ++e) { p[e] = expf(logits[e] - mx); Z += p[e]; }
    const float iz = 1.f / Z;
#pragma unroll
    for (int e = 0; e < 16; ++e) p[e] *= iz;
    int i1 = 0;
#pragma unroll
    for (int e = 1; e < 16; ++e) if (p[e] > p[i1]) i1 = e;
    int i2 = (i1 == 0) ? 1 : 0;
#pragma unroll
    for (int e = 0; e < 16; ++e) if (e != i1 && p[e] > p[i2]) i2 = e;
    const float sw = p[i1] + p[i2];
    topi[2 * n] = i1; topi[2 * n + 1] = i2;
    topw[2 * n] = p[i1] / sw; topw[2 * n + 1] = p[i2] / sw;
    float* pr = probs + (size_t)n * 16;
#pragma unroll
    for (int e = 0; e < 16; ++e) pr[e] = p[e];
  }
}

// ---------------- psum reduction (single block) ----------------
__global__ __launch_bounds__(256) void psum_k(const float* __restrict__ probs,
                                              float* __restrict__ psum) {
  float acc[16] = {};
  for (int n = threadIdx.x; n < 4096; n += 256) {
    const float4* pr = (const float4*)(probs + (size_t)n * 16);
#pragma unroll
    for (int q = 0; q < 4; ++q) {
      const float4 v = pr[q];
      acc[q * 4 + 0] += v.x; acc[q * 4 + 1] += v.y;
      acc[q * 4 + 2] += v.z; acc[q * 4 + 3] += v.w;
    }
  }
#pragma unroll
  for (int e = 0; e < 16; ++e)
#pragma unroll
    for (int o = 32; o > 0; o >>= 1) acc[e] += __shfl_down(acc[e], o);
  __shared__ float red[4][16];
  if ((threadIdx.x & 63) == 0) {
#pragma unroll
    for (int e = 0; e < 16; ++e) red[threadIdx.x >> 6][e] = acc[e];
  }
  __syncthreads();
  if (threadIdx.x < 16)
    psum[threadIdx.x] = red[0][threadIdx.x] + red[1][threadIdx.x] +
                        red[2][threadIdx.x] + red[3][threadIdx.x];
}

// ---------------- Parallel capacity scan (order-exact); also emits cnt ----------------
__global__ __launch_bounds__(256) void pos_k(const int* __restrict__ topi,
                                             const float* __restrict__ topw,
                                             int* __restrict__ slot,
                                             int* __restrict__ keep,
                                             int* __restrict__ s2t,
                                             float* __restrict__ s2w,
                                             float* __restrict__ cnt) {
  __shared__ int fi[8192];
  __shared__ int hist[256][16];
  __shared__ int total[16];
  const int t = threadIdx.x;
  for (int i = t; i < 8192; i += 256) fi[i] = topi[i];
#pragma unroll
  for (int e = 0; e < 16; ++e) hist[t][e] = 0;
  __syncthreads();
  const int base = t * 32;
#pragma unroll 8
  for (int i = 0; i < 32; ++i) hist[t][fi[base + i]]++;
  __syncthreads();
  if (t < 16) {
    int run = 0;
    for (int c = 0; c < 256; ++c) { const int v = hist[c][t]; hist[c][t] = run; run += v; }
    total[t] = run;
    cnt[t] = (float)run;
  }
  __syncthreads();
  int run[16];
#pragma unroll
  for (int e = 0; e < 16; ++e) run[e] = hist[t][e];
  for (int i = 0; i < 32; ++i) {
    const int idx = base + i;
    const int e = fi[idx];
    const int p = run[e]++;
    if (p < 640) {
      slot[idx] = p; keep[idx] = 1;
      s2t[e * 640 + p] = idx >> 1;
      s2w[e * 640 + p] = topw[idx];
    } else {
      slot[idx] = 639; keep[idx] = 0;
    }
  }
  __syncthreads();
  for (int pos = t; pos < 16 * 640; pos += 256) {
    const int e = pos / 640, c = pos - e * 640;
    if (c >= total[e]) s2t[pos] = -1;
  }
}

__global__ __launch_bounds__(128) void scatter_b_k(const unsigned short* __restrict__ xnb,
                                                   const int* __restrict__ topi,
                                                   const int* __restrict__ slot,
                                                   const int* __restrict__ keep,
                                                   unsigned short* __restrict__ buf) {
  const int i = blockIdx.x;
  if (!keep[i]) return;
  const int n = i >> 1;
  const size_t dst = ((size_t)topi[i] * 640 + slot[i]) * 1024;
  ((uint4*)(buf + dst))[threadIdx.x] = ((const uint4*)(xnb + (size_t)n * 1024))[threadIdx.x];
}

__global__ void aux_k(const float* __restrict__ cnt, const float* __restrict__ psum,
                      float* __restrict__ out) {
  if (threadIdx.x == 0) {
    float s = 0.f;
    for (int e = 0; e < 16; ++e)
      s += (cnt[e] * (1.f / 4096.f)) * (psum[e] * (1.f / 4096.f));
    out[0] = 16.f * s;
  }
}

// ---------------- tou softmax (fp32 in -> bf16 probs) + gate ----------------
__global__ __launch_bounds__(256) void softmax512_k(const float* __restrict__ sc,
                                                    unsigned short* __restrict__ out) {
  const long n = blockIdx.x;
  const float2* row = (const float2*)(sc + n * 512);
  const int t = threadIdx.x;
  float2 v = row[t];
  float mx = fmaxf(v.x, v.y);
#pragma unroll
  for (int o = 32; o > 0; o >>= 1) mx = fmaxf(mx, __shfl_down(mx, o));
  __shared__ float red[4];
  __shared__ float bm, bz;
  if ((t & 63) == 0) red[t >> 6] = mx;
  __syncthreads();
  if (t == 0) bm = fmaxf(fmaxf(red[0], red[1]), fmaxf(red[2], red[3]));
  __syncthreads();
  const float M = bm;
  const float e0 = expf(v.x - M), e1 = expf(v.y - M);
  float s = e0 + e1;
#pragma unroll
  for (int o = 32; o > 0; o >>= 1) s += __shfl_down(s, o);
  if ((t & 63) == 0) red[t >> 6] = s;
  __syncthreads();
  if (t == 0) bz = 1.f / (red[0] + red[1] + red[2] + red[3]);
  __syncthreads();
  ushort2 u; u.x = f2bf(e0 * bz); u.y = f2bf(e1 * bz);
  *(ushort2*)(out + n * 512 + t * 2) = u;
}

__global__ __launch_bounds__(256) void gate_k(const float* __restrict__ xn,
                                              const float* __restrict__ gw,
                                              const float* __restrict__ gb,
                                              float* __restrict__ gate) {
  const long n = blockIdx.x;
  const int t = threadIdx.x;
  const float4 v = ((const float4*)(xn + n * 1024))[t];
  const float4 g = ((const float4*)gw)[t];
  float s = v.x * g.x + v.y * g.y + v.z * g.z + v.w * g.w;
#pragma unroll
  for (int o = 32; o > 0; o >>= 1) s += __shfl_down(s, o);
  __shared__ float red[4];
  if ((t & 63) == 0) red[t >> 6] = s;
  __syncthreads();
  if (t == 0) {
    const float tot = red[0] + red[1] + red[2] + red[3] + gb[0];
    gate[n] = 1.f / (1.f + expf(-tot));
  }
}

extern "C" void kernel_launch(void* const* d_in, const int* in_sizes, int n_in,
                              void* d_out, int out_size, void* d_ws, size_t ws_size,
                              hipStream_t stream) {
  (void)in_sizes; (void)n_in; (void)out_size; (void)ws_size;
  const float* x    = (const float*)d_in[0];
  const float* prim = (const float*)d_in[1];
  const float* n1w  = (const float*)d_in[2];
  const float* qkvw = (const float*)d_in[3];
  const float* aow  = (const float*)d_in[4];
  const float* n2w  = (const float*)d_in[5];
  const float* rw   = (const float*)d_in[6];
  const float* w1   = (const float*)d_in[7];
  const float* w2   = (const float*)d_in[8];
  const float* n3w  = (const float*)d_in[9];
  const float* tqw  = (const float*)d_in[10];
  const float* tkw  = (const float*)d_in[11];
  const float* tvw  = (const float*)d_in[12];
  const float* tow  = (const float*)d_in[13];
  const float* tgw  = (const float*)d_in[14];
  const float* tgb  = (const float*)d_in[15];

  float* xbuf = (float*)d_out;
  float* aux  = xbuf + 4194304;

  char* W = (char*)d_ws;
  float* xn            = (float*)W;                           // 16 MB
  unsigned short* xnb  = (unsigned short*)(W + (16u << 20));  // 8 MB (hi)
  unsigned short* xnl  = (unsigned short*)(W + (24u << 20));  // 8 MB (lo)
  char* P = W + (32u << 20);

  // phase A
  float* qkv           = (float*)P;                           // 48 MB
  unsigned short* qh   = (unsigned short*)(P + (48u << 20));
  unsigned short* ql   = (unsigned short*)(P + (56u << 20));
  unsigned short* kh   = (unsigned short*)(P + (64u << 20));
  unsigned short* kl   = (unsigned short*)(P + (72u << 20));
  unsigned short* vh   = (unsigned short*)(P + (80u << 20));
  unsigned short* vl   = (unsigned short*)(P + (88u << 20));
  unsigned short* axh  = (unsigned short*)(P + (112u << 20));
  unsigned short* axl  = (unsigned short*)(P + (120u << 20));
  unsigned short* qwh  = (unsigned short*)(P + (128u << 20));
  unsigned short* qwl  = (unsigned short*)(P + (134u << 20));
  unsigned short* aoh  = (unsigned short*)(P + (140u << 20));
  unsigned short* aol  = (unsigned short*)(P + (142u << 20));
  // phase B (aliases phase A)
  int*   topi = (int*)P;
  float* topw = (float*)(P + 65536);
  int*   slot = (int*)(P + 131072);
  int*   keep = (int*)(P + 196608);
  float* cnt  = (float*)(P + 262144);
  float* psum = (float*)(P + 262144 + 4096);
  int*   s2t  = (int*)(P + 327680);
  float* s2w  = (float*)(P + 393216);
  float* probs = (float*)(P + 458752);                        // 256 KB
  unsigned short* bufb = (unsigned short*)(P + (1u << 20));   // 21 MB
  unsigned short* hb   = (unsigned short*)(P + (22u << 20));  // 42 MB
  unsigned short* Wt   = (unsigned short*)(P + (64u << 20));  // 67 MB
  // phase C (aliases again)
  unsigned short* tqb  = (unsigned short*)P;
  unsigned short* tkb  = (unsigned short*)(P + (2u << 20));
  unsigned short* tvtb = (unsigned short*)(P + (3u << 20));
  float*          tsc  = (float*)(P + (4u << 20));
  unsigned short* tpb  = (unsigned short*)(P + (12u << 20));
  unsigned short* tavb = (unsigned short*)(P + (16u << 20));
  float*          gate = (float*)(P + (18u << 20));
  unsigned short* tqwb = (unsigned short*)(P + (19u << 20));
  unsigned short* tkwb = (unsigned short*)(P + (20u << 20));
  unsigned short* tvwb = (unsigned short*)(P + (21u << 20));
  unsigned short* towb = (unsigned short*)(P + (22u << 20));
  unsigned short* primb= (unsigned short*)(P + (23u << 20));

  // ---- phase A: x += rope_attention(rmsnorm(x)) ----
  hipMemcpyAsync(xbuf, x, (size_t)4194304 * 4, hipMemcpyDeviceToDevice, stream);
  rmsnorm_k<<<4096, 256, 0, stream>>>(xbuf, n1w, xn, xnb);
  split_k<<<4096, 256, 0, stream>>>(xn, xnb, xnl, 1048576);
  split_k<<<3072, 256, 0, stream>>>(qkvw, qwh, qwl, 786432);
  split_k<<<1024, 256, 0, stream>>>(aow, aoh, aol, 262144);
  bgemm_s<0><<<dim3(24, 32, 1), 256, 0, stream>>>(xnb, xnl, qwh, qwl, qkv, 4096, 3072, 1024);
  rope_split6_k<<<4096, 256, 0, stream>>>(qkv, qh, ql, kh, kl, vh, vl);
  flash_k<<<dim3(32, 32), 256, 0, stream>>>(qh, ql, kh, kl, vh, vl, axh, axl);
  bgemm_s<1><<<dim3(8, 32, 1), 256, 0, stream>>>(axh, axl, aoh, aol, xbuf, 4096, 1024, 1024);

  // ---- phase B: MoE ----
  rmsnorm_k<<<4096, 256, 0, stream>>>(xbuf, n2w, xn, xnb);
  router_k<<<4096, 256, 0, stream>>>(xn, rw, topi, topw, probs);
  psum_k<<<1, 256, 0, stream>>>(probs, psum);
  pos_k<<<1, 256, 0, stream>>>(topi, topw, slot, keep, s2t, s2w, cnt);
  hipMemsetAsync(bufb, 0, (size_t)16 * 640 * 1024 * 2, stream);
  scatter_b_k<<<8192, 128, 0, stream>>>(xnb, topi, slot, keep, bufb);
  cvt_t_k<<<dim3(64, 32, 16), 256, 0, stream>>>(w1, Wt, 1024, 2048);
  bgemm<3><<<dim3(16, 5, 16), 256, 0, stream>>>(bufb, Wt, hb, 640, 2048, 1024,
      (long)640 * 1024, (long)2048 * 1024, (long)640 * 2048, 1.f, nullptr, nullptr, nullptr);
  cvt_t_k<<<dim3(32, 64, 16), 256, 0, stream>>>(w2, Wt, 2048, 1024);
  bgemm<5><<<dim3(8, 5, 16), 256, 0, stream>>>(hb, Wt, xbuf, 640, 1024, 2048,
      (long)640 * 2048, (long)1024 * 2048, 0, 1.f, nullptr, s2t, s2w);
  aux_k<<<1, 64, 0, stream>>>(cnt, psum, aux);

  // ---- phase C: tou cross-attn ----
  rmsnorm_k<<<4096, 256, 0, stream>>>(xbuf, n3w, xn, xnb);
  cvt_k<<<256, 256, 0, stream>>>(tqw, tqwb, 65536);
  cvt_k<<<64, 256, 0, stream>>>(tkw, tkwb, 16384);
  cvt_k<<<64, 256, 0, stream>>>(tvw, tvwb, 16384);
  cvt_k<<<256, 256, 0, stream>>>(tow, towb, 65536);
  cvt_k<<<128, 256, 0, stream>>>(prim, primb, 32768);
  bgemm<2><<<dim3(2, 32, 1), 256, 0, stream>>>(xnb, tqwb, tqb, 4096, 256, 1024, 0, 0, 0, 1.f, nullptr, nullptr, nullptr);
  bgemm<2><<<dim3(2, 4, 1), 256, 0, stream>>>(primb, tkwb, tkb, 512, 256, 256, 0, 0, 0, 1.f, nullptr, nullptr, nullptr);
  bgemm<2><<<dim3(4, 2, 1), 256, 0, stream>>>(tvwb, primb, tvtb, 256, 512, 256, 0, 0, 0, 1.f, nullptr, nullptr, nullptr);
  bgemm<0><<<dim3(4, 32, 1), 256, 0, stream>>>(tqb, tkb, tsc, 4096, 512, 256, 0, 0, 0, 0.0625f, nullptr, nullptr, nullptr);
  softmax512_k<<<4096, 256, 0, stream>>>(tsc, tpb);
  bgemm<2><<<dim3(2, 32, 1), 256, 0, stream>>>(tpb, tvtb, tavb, 4096, 256, 512, 0, 0, 0, 1.f, nullptr, nullptr, nullptr);
  gate_k<<<4096, 256, 0, stream>>>(xn, tgw, tgb, gate);
  bgemm<4><<<dim3(8, 32, 1), 256, 0, stream>>>(tavb, towb, xbuf, 4096, 1024, 256, 0, 0, 0, 1.f, gate, nullptr, nullptr);
}